// Round 4
// baseline (1926.496 us; speedup 1.0000x reference)
//
#include <hip/hip_runtime.h>
#include <math.h>

// Problem constants
#define BB 64
#define LL 24
#define DD 512
#define GG 2560        // 5*H
#define NSTEP 23       // LL-1
#define NBLKAB 224     // 64 A-blocks + 160 B-blocks
#define NSTRIPES 16
#define NBSTRIDE 32    // ints between barrier stripes (128 B)

__device__ __forceinline__ float sigm(float x) { return 1.0f / (1.0f + __expf(-x)); }

// bf16 split helpers (RNE)
__device__ __forceinline__ unsigned short f2bf(float x) {
    unsigned u = __float_as_uint(x);
    unsigned r = (u + 0x7fff + ((u >> 16) & 1)) >> 16;
    return (unsigned short)r;
}
__device__ __forceinline__ float bf2f(unsigned short b) {
    return __uint_as_float(((unsigned)b) << 16);
}

using short8 = __attribute__((ext_vector_type(8))) short;
using f32x4 = __attribute__((ext_vector_type(4))) float;
typedef unsigned long long u64;

// agent-coherent (sc0 sc1) 4B store / 16B load — cross-XCD visible without L2 flush
__device__ __forceinline__ void st4cg(unsigned short* p, unsigned v) {
    __hip_atomic_store((unsigned*)p, v, __ATOMIC_RELAXED, __HIP_MEMORY_SCOPE_AGENT);
}
__device__ __forceinline__ short8 ld8cg(const unsigned short* p) {
    union { u64 u[2]; short8 v; } t;
    t.u[0] = __hip_atomic_load((const u64*)p, __ATOMIC_RELAXED, __HIP_MEMORY_SCOPE_AGENT);
    t.u[1] = __hip_atomic_load((const u64*)p + 1, __ATOMIC_RELAXED, __HIP_MEMORY_SCOPE_AGENT);
    return t.v;
}

// ---------------------------------------------------------------------------
// one-time: split comp_W into bf16 hi/lo, rearranged to [5120][512]
// ---------------------------------------------------------------------------
__global__ __launch_bounds__(256) void splitW_k(const float* __restrict__ comp_W,
                                                unsigned short* __restrict__ Wh,
                                                unsigned short* __restrict__ Wl) {
    int t = (blockIdx.x * 256 + threadIdx.x) * 4;
    int n = t >> 9;
    int k = t & 511;
    const float* src = (n < GG) ? (comp_W + (size_t)n * (2 * DD) + k)
                                : (comp_W + (size_t)(n - GG) * (2 * DD) + DD + k);
    float4 v = *(const float4*)src;
    ushort4 h, l;
    h.x = f2bf(v.x); l.x = f2bf(v.x - bf2f(h.x));
    h.y = f2bf(v.y); l.y = f2bf(v.y - bf2f(h.y));
    h.z = f2bf(v.z); l.z = f2bf(v.z - bf2f(h.z));
    h.w = f2bf(v.w); l.w = f2bf(v.w - bf2f(h.w));
    *(ushort4*)(Wh + t) = h;
    *(ushort4*)(Wl + t) = l;
}

// ---------------------------------------------------------------------------
// fp32 GEMM, 64x128 tile — word projection. h-part -> bf16 hi/lo, c-part fp32.
// ---------------------------------------------------------------------------
__global__ __launch_bounds__(256) void gemm64w(const float* __restrict__ A,
                                               const float* __restrict__ Wt,
                                               const float* __restrict__ bias,
                                               unsigned short* __restrict__ Ah,
                                               unsigned short* __restrict__ Al,
                                               float* __restrict__ O1) {
    __shared__ float As[16][68];
    __shared__ float Bs[16][132];
    const int tid = threadIdx.x;
    const int n0 = blockIdx.x * 128;
    const int m0 = blockIdx.y * 64;
    const int tn = tid & 15;
    const int tm = tid >> 4;

    float acc[4][8];
#pragma unroll
    for (int y = 0; y < 4; ++y)
#pragma unroll
        for (int x = 0; x < 8; ++x) acc[y][x] = 0.f;

    for (int kt = 0; kt < 512; kt += 16) {
        {
            int r = tid >> 2, c4 = tid & 3;
            float4 v = *(const float4*)(A + (size_t)(m0 + r) * DD + kt + c4 * 4);
            As[c4 * 4 + 0][r] = v.x;
            As[c4 * 4 + 1][r] = v.y;
            As[c4 * 4 + 2][r] = v.z;
            As[c4 * 4 + 3][r] = v.w;
        }
#pragma unroll
        for (int ii = 0; ii < 2; ++ii) {
            int idx = tid + ii * 256;
            int r = idx >> 2, c4 = idx & 3;
            float4 v = *(const float4*)(Wt + (size_t)(n0 + r) * DD + kt + c4 * 4);
            Bs[c4 * 4 + 0][r] = v.x;
            Bs[c4 * 4 + 1][r] = v.y;
            Bs[c4 * 4 + 2][r] = v.z;
            Bs[c4 * 4 + 3][r] = v.w;
        }
        __syncthreads();
#pragma unroll
        for (int k = 0; k < 16; ++k) {
            float4 a = *(const float4*)&As[k][tm * 4];
            float4 b0 = *(const float4*)&Bs[k][tn * 4];
            float4 b1 = *(const float4*)&Bs[k][64 + tn * 4];
            float av[4] = {a.x, a.y, a.z, a.w};
            float bv[8] = {b0.x, b0.y, b0.z, b0.w, b1.x, b1.y, b1.z, b1.w};
#pragma unroll
            for (int y = 0; y < 4; ++y)
#pragma unroll
                for (int x = 0; x < 8; ++x) acc[y][x] += av[y] * bv[x];
        }
        __syncthreads();
    }

#pragma unroll
    for (int y = 0; y < 4; ++y) {
        const int m = m0 + tm * 4 + y;
#pragma unroll
        for (int g = 0; g < 2; ++g) {
            int n = n0 + g * 64 + tn * 4;
            float4 v;
            v.x = acc[y][g * 4 + 0] + bias[n + 0];
            v.y = acc[y][g * 4 + 1] + bias[n + 1];
            v.z = acc[y][g * 4 + 2] + bias[n + 2];
            v.w = acc[y][g * 4 + 3] + bias[n + 3];
            if (n < DD) {
                ushort4 hv, lv;
                hv.x = f2bf(v.x); lv.x = f2bf(v.x - bf2f(hv.x));
                hv.y = f2bf(v.y); lv.y = f2bf(v.y - bf2f(hv.y));
                hv.z = f2bf(v.z); lv.z = f2bf(v.z - bf2f(hv.z));
                hv.w = f2bf(v.w); lv.w = f2bf(v.w - bf2f(hv.w));
                *(ushort4*)(Ah + (size_t)m * DD + n) = hv;
                *(ushort4*)(Al + (size_t)m * DD + n) = lv;
            } else {
                *(float4*)(O1 + (size_t)m * DD + (n - DD)) = v;
            }
        }
    }
}

// ---------------------------------------------------------------------------
// a/b cache GEMM via bf16x3 MFMA. M=1536, N=5120, K=512. (round-3 verified)
// ---------------------------------------------------------------------------
__global__ __launch_bounds__(256) void gemm_big_mfma(
    const unsigned short* __restrict__ Ah, const unsigned short* __restrict__ Al,
    const unsigned short* __restrict__ Wh, const unsigned short* __restrict__ Wl,
    float* __restrict__ O0, float* __restrict__ O1) {
    const int tid = threadIdx.x;
    const int n0 = blockIdx.x * 128;
    const int m0 = blockIdx.y * 128;
    const int w = tid >> 6, lane = tid & 63;
    const int mq = w >> 1, nq = w & 1;
    const int lr = lane & 15, kg = lane >> 4;
    const int kofs = kg * 8;

    const unsigned short* pah[4];
    const unsigned short* pal[4];
    const unsigned short* pbh[4];
    const unsigned short* pbl[4];
#pragma unroll
    for (int t = 0; t < 4; ++t) {
        int mrow = m0 + mq * 64 + t * 16 + lr;
        pah[t] = Ah + (size_t)mrow * DD + kofs;
        pal[t] = Al + (size_t)mrow * DD + kofs;
        int nrow = n0 + nq * 64 + t * 16 + lr;
        pbh[t] = Wh + (size_t)nrow * DD + kofs;
        pbl[t] = Wl + (size_t)nrow * DD + kofs;
    }

    f32x4 acc[4][4];
#pragma unroll
    for (int mt = 0; mt < 4; ++mt)
#pragma unroll
        for (int nt = 0; nt < 4; ++nt) acc[mt][nt] = (f32x4){0.f, 0.f, 0.f, 0.f};

#pragma unroll 2
    for (int ks = 0; ks < 16; ++ks) {
        const int kb = ks * 32;
        short8 ah[4], al[4], bh[4], bl[4];
#pragma unroll
        for (int t = 0; t < 4; ++t) {
            ah[t] = *(const short8*)(pah[t] + kb);
            al[t] = *(const short8*)(pal[t] + kb);
            bh[t] = *(const short8*)(pbh[t] + kb);
            bl[t] = *(const short8*)(pbl[t] + kb);
        }
#pragma unroll
        for (int mt = 0; mt < 4; ++mt)
#pragma unroll
            for (int nt = 0; nt < 4; ++nt) {
                acc[mt][nt] = __builtin_amdgcn_mfma_f32_16x16x32_bf16(al[mt], bh[nt], acc[mt][nt], 0, 0, 0);
                acc[mt][nt] = __builtin_amdgcn_mfma_f32_16x16x32_bf16(ah[mt], bl[nt], acc[mt][nt], 0, 0, 0);
                acc[mt][nt] = __builtin_amdgcn_mfma_f32_16x16x32_bf16(ah[mt], bh[nt], acc[mt][nt], 0, 0, 0);
            }
    }

#pragma unroll
    for (int mt = 0; mt < 4; ++mt) {
        const int mbase = m0 + mq * 64 + mt * 16 + kg * 4;
#pragma unroll
        for (int nt = 0; nt < 4; ++nt) {
            const int n = n0 + nq * 64 + nt * 16 + lr;
#pragma unroll
            for (int r = 0; r < 4; ++r) {
                const int m = mbase + r;
                float* dst = (n < GG) ? (O0 + (size_t)m * GG + n)
                                      : (O1 + (size_t)m * GG + (n - GG));
                *dst = acc[mt][nt][r];
            }
        }
    }
}

// ---------------------------------------------------------------------------
// half-block (128-lane) candidate scorer
// ---------------------------------------------------------------------------
__device__ __forceinline__ float half_dot(const float* __restrict__ ar,
                                          const float* __restrict__ br,
                                          const float* __restrict__ cb,
                                          const float* __restrict__ cl,
                                          const float* __restrict__ cr,
                                          const float* __restrict__ q, int lane) {
    float part = 0.f;
#pragma unroll
    for (int d = lane; d < DD; d += 128) {
        float gi = ar[d] + br[d] + cb[d];
        float gfl = ar[DD + d] + br[DD + d] + cb[DD + d];
        float gfr = ar[2 * DD + d] + br[2 * DD + d] + cb[2 * DD + d];
        float gu = ar[3 * DD + d] + br[3 * DD + d] + cb[3 * DD + d];
        float go = ar[4 * DD + d] + br[4 * DD + d] + cb[4 * DD + d];
        float nc = cl[d] * sigm(gfl + 1.f) + cr[d] * sigm(gfr + 1.f) + tanhf(gu) * sigm(gi);
        part += sigm(go) * tanhf(nc) * q[d];
    }
#pragma unroll
    for (int off = 32; off; off >>= 1) part += __shfl_down(part, off);
    return part;
}

// gate pair
__device__ __forceinline__ void gate2n(const float* __restrict__ ar,
                                       const float* __restrict__ br,
                                       const float* __restrict__ cb,
                                       const float* __restrict__ cl,
                                       const float* __restrict__ cr, int d,
                                       float nh[2], float nc[2]) {
    float2 A0 = *(const float2*)(ar + d),          B0 = *(const float2*)(br + d);
    float2 A1 = *(const float2*)(ar + DD + d),     B1 = *(const float2*)(br + DD + d);
    float2 A2 = *(const float2*)(ar + 2 * DD + d), B2 = *(const float2*)(br + 2 * DD + d);
    float2 A3 = *(const float2*)(ar + 3 * DD + d), B3 = *(const float2*)(br + 3 * DD + d);
    float2 A4 = *(const float2*)(ar + 4 * DD + d), B4 = *(const float2*)(br + 4 * DD + d);
    float2 C0 = *(const float2*)(cb + d);
    float2 C1 = *(const float2*)(cb + DD + d);
    float2 C2 = *(const float2*)(cb + 2 * DD + d);
    float2 C3 = *(const float2*)(cb + 3 * DD + d);
    float2 C4 = *(const float2*)(cb + 4 * DD + d);
    float2 CL = *(const float2*)(cl + d);
    float2 CR = *(const float2*)(cr + d);
    float gi0 = A0.x + B0.x + C0.x, gi1 = A0.y + B0.y + C0.y;
    float gfl0 = A1.x + B1.x + C1.x, gfl1 = A1.y + B1.y + C1.y;
    float gfr0 = A2.x + B2.x + C2.x, gfr1 = A2.y + B2.y + C2.y;
    float gu0 = A3.x + B3.x + C3.x, gu1 = A3.y + B3.y + C3.y;
    float go0 = A4.x + B4.x + C4.x, go1 = A4.y + B4.y + C4.y;
    nc[0] = CL.x * sigm(gfl0 + 1.f) + CR.x * sigm(gfr0 + 1.f) + tanhf(gu0) * sigm(gi0);
    nc[1] = CL.y * sigm(gfl1 + 1.f) + CR.y * sigm(gfr1 + 1.f) + tanhf(gu1) * sigm(gi1);
    nh[0] = sigm(go0) * tanhf(nc[0]);
    nh[1] = sigm(go1) * tanhf(nc[1]);
}

// ---------------------------------------------------------------------------
// initial scores: grid (12, 64). Block (0,0) also zeroes the barrier stripes.
// ---------------------------------------------------------------------------
__global__ __launch_bounds__(256) void scoreall_k(const float* __restrict__ acache,
                                                  const float* __restrict__ bcache,
                                                  const float* __restrict__ cbuf,
                                                  const float* __restrict__ compb,
                                                  const float* __restrict__ q,
                                                  float* __restrict__ scores_g,
                                                  int* __restrict__ barcnt) {
    __shared__ float red_s[4];
    const int tid = threadIdx.x;
    const int b = blockIdx.y;
    const int p = blockIdx.x * 2 + (tid >> 7);
    if (blockIdx.x == 0 && blockIdx.y == 0) {
        barcnt[tid] = 0;
        barcnt[tid + 256] = 0;
    }
    const bool valid = p < NSTEP;
    float w = 0.f;
    if (valid) {
        w = half_dot(acache + (size_t)(b * LL + p) * GG,
                     bcache + (size_t)(b * LL + p + 1) * GG, compb,
                     cbuf + (size_t)(b * LL + p) * DD,
                     cbuf + (size_t)(b * LL + p + 1) * DD, q, tid & 127);
    }
    if ((tid & 63) == 0) red_s[tid >> 6] = w;
    __syncthreads();
    if ((tid == 0 || tid == 128) && valid) {
        int base = tid >> 6;
        scores_g[b * NSTEP + p] = red_s[base] + red_s[base + 1];
    }
}

// ---------------------------------------------------------------------------
// stepAB: one launch per merge step. 224 blocks (cooperative, co-resident).
//   blocks 0..63   : phase A for batch b=bid (rescore -> argmax -> merge),
//                    write hh/hl/msel with agent-coherent stores, signal.
//   blocks 64..223 : prefetch W slice into L2, poll the barrier, then phase B
//                    (bf16x3 MFMA, 64m x 32n) reading hh/hl/msel coherently.
// B(i) -> A(i+1) ordering comes from the dispatch boundary (normal mem ops).
// Barrier: monotonic striped counter, target BB*(i+1); no threadfence.
// ---------------------------------------------------------------------------
__global__ __launch_bounds__(256) void stepAB_k(
    int i, const int* __restrict__ length, float* __restrict__ cbuf,
    float* __restrict__ acache, float* __restrict__ bcache,
    float* __restrict__ hout, unsigned short* __restrict__ hh,
    unsigned short* __restrict__ hl, float* __restrict__ scores_g,
    int* __restrict__ seq_g, int* __restrict__ kp_g, int* __restrict__ msel,
    const float* __restrict__ compb, const float* __restrict__ q,
    float* __restrict__ out,
    const unsigned short* __restrict__ Wh, const unsigned short* __restrict__ Wl,
    int* __restrict__ barcnt) {
    const int tid = threadIdx.x;
    const int bid = blockIdx.x;

    if (bid < BB) {
        // ===================== phase A =====================
        __shared__ float red_s[4];
        __shared__ float sc_l[32];
        __shared__ int seq_l[32];
        __shared__ int k_sh;
        const int b = bid;
        const int lane7 = tid & 127;
        const int lenb = length[b];
        const int ncand = NSTEP - i;

        if (i == 0) {
            if (tid < LL) seq_l[tid] = tid;
        } else {
            if (tid < LL - i) seq_l[tid] = seq_g[b * 32 + tid];
        }
        if (tid < ncand) sc_l[tid] = scores_g[b * NSTEP + tid];
        __syncthreads();
        const int kp = (i > 0) ? kp_g[b] : 0;

        if (i > 0 && i < lenb) {  // rescore candidates kp-1, kp
            int p = (tid < 128) ? (kp - 1) : kp;
            bool valid = (p >= 0) && (p < ncand);
            float w = 0.f;
            if (valid) {
                int sl = seq_l[p], sr = seq_l[p + 1];
                const float* ar = acache + (size_t)(b * LL + sl) * GG;
                const float* br = bcache + (size_t)(b * LL + sr) * GG;
                const float* cl = cbuf + (size_t)(b * LL + sl) * DD;
                const float* cr = cbuf + (size_t)(b * LL + sr) * DD;
#pragma unroll
                for (int pass = 0; pass < 2; ++pass) {
                    int d = pass * 256 + lane7 * 2;
                    float nh[2], nc[2];
                    gate2n(ar, br, compb, cl, cr, d, nh, nc);
                    float2 Q = *(const float2*)(q + d);
                    w += nh[0] * Q.x + nh[1] * Q.y;
                }
#pragma unroll
                for (int off = 32; off; off >>= 1) w += __shfl_down(w, off);
            }
            if ((tid & 63) == 0) red_s[tid >> 6] = w;
            __syncthreads();
            if (tid == 0) {
                if (kp - 1 >= 0) sc_l[kp - 1] = red_s[0] + red_s[1];
                if (kp < ncand) sc_l[kp] = red_s[2] + red_s[3];
            }
            __syncthreads();
        }

        if (i + 1 < lenb) {
            if (tid == 0) {
                const int vmax = lenb - i - 2;
                int k = 0;
                float best = sc_l[0];
                for (int pp = 1; pp <= vmax; ++pp)
                    if (sc_l[pp] > best) { best = sc_l[pp]; k = pp; }
                k_sh = k;
            }
            __syncthreads();
            const int k = k_sh;
            const int sl = seq_l[k], sr = seq_l[k + 1];
            const float* ar = acache + (size_t)(b * LL + sl) * GG;
            const float* br = bcache + (size_t)(b * LL + sr) * GG;
            const float* cl = cbuf + (size_t)(b * LL + sl) * DD;
            const float* cr = cbuf + (size_t)(b * LL + sr) * DD;
            {
                const int d = 2 * tid;
                float nh[2], nc[2];
                gate2n(ar, br, compb, cl, cr, d, nh, nc);
                *(float2*)(cbuf + (size_t)(b * LL + sl) * DD + d) = make_float2(nc[0], nc[1]);
                *(float2*)(hout + (size_t)b * DD + d) = make_float2(nh[0], nh[1]);
                // bf16 hi/lo split, agent-coherent (read by B-blocks this launch)
                ushort2 hv, lv;
                hv.x = f2bf(nh[0]); lv.x = f2bf(nh[0] - bf2f(hv.x));
                hv.y = f2bf(nh[1]); lv.y = f2bf(nh[1] - bf2f(hv.y));
                st4cg(hh + (size_t)b * DD + d, (unsigned)hv.x | ((unsigned)hv.y << 16));
                st4cg(hl + (size_t)b * DD + d, (unsigned)lv.x | ((unsigned)lv.y << 16));
                if (i == NSTEP - 1)
                    *(float2*)(out + (size_t)b * DD + d) = make_float2(nh[0], nh[1]);
            }
            float sv = (tid + 1 < ncand) ? sc_l[tid + 1] : 0.f;
            int qv = (tid + 1 < LL - i) ? seq_l[tid + 1] : 0;
            __syncthreads();
            if (tid >= k + 1 && tid <= ncand - 2) sc_l[tid] = sv;
            if (tid >= k + 1 && tid <= LL - i - 2) seq_l[tid] = qv;
            if (tid < ncand - 1) scores_g[b * NSTEP + tid] = sc_l[tid];
            if (tid < LL - i - 1) seq_g[b * 32 + tid] = seq_l[tid];
            if (tid == 0) {
                kp_g[b] = k;
                __hip_atomic_store(msel + b, sl, __ATOMIC_RELAXED, __HIP_MEMORY_SCOPE_AGENT);
            }
        } else if (i == NSTEP - 1) {
            const int d = 2 * tid;
            *(float2*)(out + (size_t)b * DD + d) = *(const float2*)(hout + (size_t)b * DD + d);
        }

        // arrival: all this block's (sc1) stores are drained by __syncthreads
        __syncthreads();
        if (tid == 0)
            __hip_atomic_fetch_add(barcnt + (bid & (NSTRIPES - 1)) * NBSTRIDE, 1,
                                   __ATOMIC_RELEASE, __HIP_MEMORY_SCOPE_AGENT);
        return;
    }

    // ===================== phase B =====================
    if (i == NSTEP - 1) return;   // no B work at the final step
    __shared__ int msel_s[BB];
    const int slice = bid - BB;

    // warm this slice's W rows into L2 while phase A runs (1 line/thread)
    {
        const float* ph = (const float*)(Wh + (size_t)slice * 32 * DD);
        const float* pl = (const float*)(Wl + (size_t)slice * 32 * DD);
        float pf = ph[tid * 32] + pl[tid * 32];
        asm volatile("" :: "v"(pf));
    }

    if (tid == 0) {
        const int target = BB * (i + 1);
        while (true) {
            int s = 0;
#pragma unroll
            for (int j = 0; j < NSTRIPES; ++j)
                s += __hip_atomic_load(barcnt + j * NBSTRIDE, __ATOMIC_ACQUIRE,
                                       __HIP_MEMORY_SCOPE_AGENT);
            if (s >= target) break;
            __builtin_amdgcn_s_sleep(2);
        }
    }
    __syncthreads();

    if (tid < BB)
        msel_s[tid] = __hip_atomic_load(msel + tid, __ATOMIC_RELAXED,
                                        __HIP_MEMORY_SCOPE_AGENT);
    __syncthreads();

    const int w = tid >> 6, lane = tid & 63;
    const int mt0 = (w >> 1) * 2;
    const int nt = w & 1;
    const int lr = lane & 15;
    const int kg = lane >> 4;
    const int n = slice * 32 + nt * 16 + lr;

    const unsigned short* wh_row = Wh + (size_t)n * DD;
    const unsigned short* wl_row = Wl + (size_t)n * DD;
    const unsigned short* a0h_row = hh + (size_t)(mt0 * 16 + lr) * DD;
    const unsigned short* a0l_row = hl + (size_t)(mt0 * 16 + lr) * DD;
    const unsigned short* a1h_row = a0h_row + 16 * DD;
    const unsigned short* a1l_row = a0l_row + 16 * DD;

    f32x4 acc0 = {0.f, 0.f, 0.f, 0.f};
    f32x4 acc1 = {0.f, 0.f, 0.f, 0.f};

#pragma unroll 4
    for (int ks = 0; ks < 16; ++ks) {
        const int kb = ks * 32 + kg * 8;
        short8 bh = *(const short8*)(wh_row + kb);
        short8 bl = *(const short8*)(wl_row + kb);
        short8 a0h = ld8cg(a0h_row + kb);
        short8 a0l = ld8cg(a0l_row + kb);
        short8 a1h = ld8cg(a1h_row + kb);
        short8 a1l = ld8cg(a1l_row + kb);
        acc0 = __builtin_amdgcn_mfma_f32_16x16x32_bf16(a0h, bh, acc0, 0, 0, 0);
        acc1 = __builtin_amdgcn_mfma_f32_16x16x32_bf16(a1h, bh, acc1, 0, 0, 0);
        acc0 = __builtin_amdgcn_mfma_f32_16x16x32_bf16(a0l, bh, acc0, 0, 0, 0);
        acc1 = __builtin_amdgcn_mfma_f32_16x16x32_bf16(a1l, bh, acc1, 0, 0, 0);
        acc0 = __builtin_amdgcn_mfma_f32_16x16x32_bf16(a0h, bl, acc0, 0, 0, 0);
        acc1 = __builtin_amdgcn_mfma_f32_16x16x32_bf16(a1h, bl, acc1, 0, 0, 0);
    }

#pragma unroll
    for (int t = 0; t < 2; ++t) {
        f32x4 acc = t ? acc1 : acc0;
        const int mbase = (mt0 + t) * 16 + kg * 4;
#pragma unroll
        for (int r = 0; r < 4; ++r) {
            int m = mbase + r;
            size_t row = (size_t)(m * LL + msel_s[m]);
            float* dst = (n < GG) ? (acache + row * GG + n)
                                  : (bcache + row * GG + (n - GG));
            *dst = acc[r];
        }
    }
}

// ---------------------------------------------------------------------------
extern "C" void kernel_launch(void* const* d_in, const int* in_sizes, int n_in, void* d_out,
                              int out_size, void* d_ws, size_t ws_size, hipStream_t stream) {
    const float* inp = (const float*)d_in[0];
    const int* length = (const int*)d_in[1];
    const float* word_W = (const float*)d_in[2];
    const float* word_b = (const float*)d_in[3];
    const float* comp_W = (const float*)d_in[4];
    const float* comp_b = (const float*)d_in[5];
    const float* comp_q = (const float*)d_in[6];
    float* out = (float*)d_out;

    float* ws = (float*)d_ws;
    size_t off = 0;
    float* cbuf = ws + off;   off += (size_t)BB * LL * DD;
    float* acache = ws + off; off += (size_t)BB * LL * GG;
    float* bcache = ws + off; off += (size_t)BB * LL * GG;
    float* hout = ws + off;   off += (size_t)BB * DD;
    float* scores = ws + off; off += 2048;
    int* seq_g = (int*)(ws + off); off += BB * 32;
    int* kp_g = (int*)(ws + off);  off += 64;
    int* msel = (int*)(ws + off);  off += 64;
    unsigned short* Wh = (unsigned short*)(ws + off); off += (size_t)5120 * DD / 2;
    unsigned short* Wl = (unsigned short*)(ws + off); off += (size_t)5120 * DD / 2;
    unsigned short* hh = (unsigned short*)(ws + off); off += (size_t)BB * DD / 2;
    unsigned short* hl = (unsigned short*)(ws + off); off += (size_t)BB * DD / 2;
    unsigned short* Ah = (unsigned short*)(ws + off); off += (size_t)BB * LL * DD / 2;
    unsigned short* Al = (unsigned short*)(ws + off); off += (size_t)BB * LL * DD / 2;
    int* barcnt = (int*)(ws + off); off += 512;
    (void)ws_size; (void)in_sizes; (void)n_in; (void)out_size;

    // one-time bf16 hi/lo split of comp_W (rearranged [5120][512])
    splitW_k<<<2560, 256, 0, stream>>>(comp_W, Wh, Wl);

    // word projection: h (bf16 hi/lo), c (fp32)
    gemm64w<<<dim3(8, 24), 256, 0, stream>>>(inp, word_W, word_b, Ah, Al, cbuf);

    // a/b caches for all 1536 items via bf16x3 MFMA
    gemm_big_mfma<<<dim3(40, 12), 256, 0, stream>>>(Ah, Al, Wh, Wl, acache, bcache);

    // initial candidate scores (+ barrier zero)
    scoreall_k<<<dim3(12, 64), 256, 0, stream>>>(acache, bcache, cbuf, comp_b, comp_q,
                                                 scores, barcnt);

    // 23 merge steps, one fused dispatch each (A-phase -> in-kernel barrier -> B-phase)
    for (int i = 0; i < NSTEP; ++i) {
        int ii = i;
        void* args[] = {(void*)&ii,     (void*)&length, (void*)&cbuf,   (void*)&acache,
                        (void*)&bcache, (void*)&hout,   (void*)&hh,     (void*)&hl,
                        (void*)&scores, (void*)&seq_g,  (void*)&kp_g,   (void*)&msel,
                        (void*)&comp_b, (void*)&comp_q, (void*)&out,    (void*)&Wh,
                        (void*)&Wl,     (void*)&barcnt};
        hipLaunchCooperativeKernel((const void*)stepAB_k, dim3(NBLKAB), dim3(256),
                                   args, 0, stream);
    }
}

// Round 5
// 687.090 us; speedup vs baseline: 2.8038x; 2.8038x over previous
//
#include <hip/hip_runtime.h>
#include <math.h>

// Problem constants
#define BB 64
#define LL 24
#define DD 512
#define GG 2560        // 5*H
#define NSTEP 23       // LL-1
#define NTILES 160     // stepB n-tiles: 5120/32

__device__ __forceinline__ float sigm(float x) { return 1.0f / (1.0f + __expf(-x)); }

// bf16 split helpers (RNE)
__device__ __forceinline__ unsigned short f2bf(float x) {
    unsigned u = __float_as_uint(x);
    unsigned r = (u + 0x7fff + ((u >> 16) & 1)) >> 16;
    return (unsigned short)r;
}
__device__ __forceinline__ float bf2f(unsigned short b) {
    return __uint_as_float(((unsigned)b) << 16);
}

using short8 = __attribute__((ext_vector_type(8))) short;
using f32x4 = __attribute__((ext_vector_type(4))) float;

// ---------------------------------------------------------------------------
// one-time: split comp_W into bf16 hi/lo, rearranged to [5120][512]
// row n (<2560): comp_W[n][0:512] (a-part); row n>=2560: comp_W[n-2560][512:1024]
// ---------------------------------------------------------------------------
__global__ __launch_bounds__(256) void splitW_k(const float* __restrict__ comp_W,
                                                unsigned short* __restrict__ Wh,
                                                unsigned short* __restrict__ Wl) {
    int t = (blockIdx.x * 256 + threadIdx.x) * 4;   // 5120*512 elems, 4/thread
    int n = t >> 9;
    int k = t & 511;
    const float* src = (n < GG) ? (comp_W + (size_t)n * (2 * DD) + k)
                                : (comp_W + (size_t)(n - GG) * (2 * DD) + DD + k);
    float4 v = *(const float4*)src;
    ushort4 h, l;
    h.x = f2bf(v.x); l.x = f2bf(v.x - bf2f(h.x));
    h.y = f2bf(v.y); l.y = f2bf(v.y - bf2f(h.y));
    h.z = f2bf(v.z); l.z = f2bf(v.z - bf2f(h.z));
    h.w = f2bf(v.w); l.w = f2bf(v.w - bf2f(h.w));
    *(ushort4*)(Wh + t) = h;
    *(ushort4*)(Wl + t) = l;
}

// ---------------------------------------------------------------------------
// fp32 GEMM, 64x128 tile — word projection. h-part (n<512) is written as
// bf16 hi/lo (MFMA A-operand for gemm_big_mfma); c-part (n>=512) stays fp32.
// (round-0 verified numerics)
// ---------------------------------------------------------------------------
__global__ __launch_bounds__(256) void gemm64w(const float* __restrict__ A,
                                               const float* __restrict__ Wt,
                                               const float* __restrict__ bias,
                                               unsigned short* __restrict__ Ah,
                                               unsigned short* __restrict__ Al,
                                               float* __restrict__ O1) {
    __shared__ float As[16][68];
    __shared__ float Bs[16][132];
    const int tid = threadIdx.x;
    const int n0 = blockIdx.x * 128;
    const int m0 = blockIdx.y * 64;
    const int tn = tid & 15;
    const int tm = tid >> 4;

    float acc[4][8];
#pragma unroll
    for (int y = 0; y < 4; ++y)
#pragma unroll
        for (int x = 0; x < 8; ++x) acc[y][x] = 0.f;

    for (int kt = 0; kt < 512; kt += 16) {
        {
            int r = tid >> 2, c4 = tid & 3;
            float4 v = *(const float4*)(A + (size_t)(m0 + r) * DD + kt + c4 * 4);
            As[c4 * 4 + 0][r] = v.x;
            As[c4 * 4 + 1][r] = v.y;
            As[c4 * 4 + 2][r] = v.z;
            As[c4 * 4 + 3][r] = v.w;
        }
#pragma unroll
        for (int ii = 0; ii < 2; ++ii) {
            int idx = tid + ii * 256;
            int r = idx >> 2, c4 = idx & 3;
            float4 v = *(const float4*)(Wt + (size_t)(n0 + r) * DD + kt + c4 * 4);
            Bs[c4 * 4 + 0][r] = v.x;
            Bs[c4 * 4 + 1][r] = v.y;
            Bs[c4 * 4 + 2][r] = v.z;
            Bs[c4 * 4 + 3][r] = v.w;
        }
        __syncthreads();
#pragma unroll
        for (int k = 0; k < 16; ++k) {
            float4 a = *(const float4*)&As[k][tm * 4];
            float4 b0 = *(const float4*)&Bs[k][tn * 4];
            float4 b1 = *(const float4*)&Bs[k][64 + tn * 4];
            float av[4] = {a.x, a.y, a.z, a.w};
            float bv[8] = {b0.x, b0.y, b0.z, b0.w, b1.x, b1.y, b1.z, b1.w};
#pragma unroll
            for (int y = 0; y < 4; ++y)
#pragma unroll
                for (int x = 0; x < 8; ++x) acc[y][x] += av[y] * bv[x];
        }
        __syncthreads();
    }

#pragma unroll
    for (int y = 0; y < 4; ++y) {
        const int m = m0 + tm * 4 + y;
#pragma unroll
        for (int g = 0; g < 2; ++g) {
            int n = n0 + g * 64 + tn * 4;
            float4 v;
            v.x = acc[y][g * 4 + 0] + bias[n + 0];
            v.y = acc[y][g * 4 + 1] + bias[n + 1];
            v.z = acc[y][g * 4 + 2] + bias[n + 2];
            v.w = acc[y][g * 4 + 3] + bias[n + 3];
            if (n < DD) {
                ushort4 hv, lv;
                hv.x = f2bf(v.x); lv.x = f2bf(v.x - bf2f(hv.x));
                hv.y = f2bf(v.y); lv.y = f2bf(v.y - bf2f(hv.y));
                hv.z = f2bf(v.z); lv.z = f2bf(v.z - bf2f(hv.z));
                hv.w = f2bf(v.w); lv.w = f2bf(v.w - bf2f(hv.w));
                *(ushort4*)(Ah + (size_t)m * DD + n) = hv;
                *(ushort4*)(Al + (size_t)m * DD + n) = lv;
            } else {
                *(float4*)(O1 + (size_t)m * DD + (n - DD)) = v;
            }
        }
    }
}

// ---------------------------------------------------------------------------
// gemm_big_mfma v2: a/b cache GEMM via bf16x3 MFMA. M=1536, N=5120, K=512.
// 960 blocks (64m x 128n tile), XCD-swizzled (960%8==0 -> bijective), 4 waves
// per block each owning 64m x 32n (4x2 16-tiles). Register double-buffered:
// K-step s+1's 12 fragments load while K-step s's 24 MFMAs issue. All
// fragment buffers statically indexed (named f0/f1) to stay in registers.
// ---------------------------------------------------------------------------
struct Frag {
    short8 ah[4], al[4], bh[2], bl[2];
};

__device__ __forceinline__ void frag_load(Frag& f,
                                          const unsigned short* const pah[4],
                                          const unsigned short* const pal[4],
                                          const unsigned short* const pbh[2],
                                          const unsigned short* const pbl[2],
                                          int kb) {
#pragma unroll
    for (int t = 0; t < 4; ++t) {
        f.ah[t] = *(const short8*)(pah[t] + kb);
        f.al[t] = *(const short8*)(pal[t] + kb);
    }
#pragma unroll
    for (int u = 0; u < 2; ++u) {
        f.bh[u] = *(const short8*)(pbh[u] + kb);
        f.bl[u] = *(const short8*)(pbl[u] + kb);
    }
}

__device__ __forceinline__ void frag_mma(const Frag& f, f32x4 acc[4][2]) {
#pragma unroll
    for (int t = 0; t < 4; ++t)
#pragma unroll
        for (int u = 0; u < 2; ++u) {
            acc[t][u] = __builtin_amdgcn_mfma_f32_16x16x32_bf16(f.al[t], f.bh[u], acc[t][u], 0, 0, 0);
            acc[t][u] = __builtin_amdgcn_mfma_f32_16x16x32_bf16(f.ah[t], f.bl[u], acc[t][u], 0, 0, 0);
            acc[t][u] = __builtin_amdgcn_mfma_f32_16x16x32_bf16(f.ah[t], f.bh[u], acc[t][u], 0, 0, 0);
        }
}

__global__ __launch_bounds__(256) void gemm_big_mfma(
    const unsigned short* __restrict__ Ah, const unsigned short* __restrict__ Al,
    const unsigned short* __restrict__ Wh, const unsigned short* __restrict__ Wl,
    float* __restrict__ O0, float* __restrict__ O1) {
    const int tid = threadIdx.x;
    // XCD swizzle: XCD j owns wg in [j*120, (j+1)*120) -> contiguous n-range
    const int flat = blockIdx.x;
    const int wg = (flat & 7) * 120 + (flat >> 3);
    const int m0 = (wg % 24) * 64;
    const int n0 = (wg / 24) * 128;
    const int w = tid >> 6, lane = tid & 63;
    const int lr = lane & 15, kg = lane >> 4;
    const int kofs = kg * 8;

    const unsigned short* pah[4];
    const unsigned short* pal[4];
    const unsigned short* pbh[2];
    const unsigned short* pbl[2];
#pragma unroll
    for (int t = 0; t < 4; ++t) {
        int mrow = m0 + t * 16 + lr;
        pah[t] = Ah + (size_t)mrow * DD + kofs;
        pal[t] = Al + (size_t)mrow * DD + kofs;
    }
#pragma unroll
    for (int u = 0; u < 2; ++u) {
        int nrow = n0 + w * 32 + u * 16 + lr;
        pbh[u] = Wh + (size_t)nrow * DD + kofs;
        pbl[u] = Wl + (size_t)nrow * DD + kofs;
    }

    f32x4 acc[4][2];
#pragma unroll
    for (int t = 0; t < 4; ++t)
#pragma unroll
        for (int u = 0; u < 2; ++u) acc[t][u] = (f32x4){0.f, 0.f, 0.f, 0.f};

    Frag f0, f1;
    frag_load(f0, pah, pal, pbh, pbl, 0);
#pragma unroll
    for (int ks = 0; ks < 16; ks += 2) {
        if (ks + 1 < 16) frag_load(f1, pah, pal, pbh, pbl, (ks + 1) * 32);
        frag_mma(f0, acc);
        if (ks + 2 < 16) frag_load(f0, pah, pal, pbh, pbl, (ks + 2) * 32);
        if (ks + 1 < 16) frag_mma(f1, acc);
    }

    // C/D layout: col = lane&15, row = (lane>>4)*4 + reg   [verified]
#pragma unroll
    for (int t = 0; t < 4; ++t) {
        const int mbase = m0 + t * 16 + kg * 4;
#pragma unroll
        for (int u = 0; u < 2; ++u) {
            const int n = n0 + w * 32 + u * 16 + lr;
#pragma unroll
            for (int r = 0; r < 4; ++r) {
                const int m = mbase + r;
                float* dst = (n < GG) ? (O0 + (size_t)m * GG + n)
                                      : (O1 + (size_t)m * GG + (n - GG));
                *dst = acc[t][u][r];
            }
        }
    }
}

// ---------------------------------------------------------------------------
// half-block (128-lane) candidate scorer
// ---------------------------------------------------------------------------
__device__ __forceinline__ float half_dot(const float* __restrict__ ar,
                                          const float* __restrict__ br,
                                          const float* __restrict__ cb,
                                          const float* __restrict__ cl,
                                          const float* __restrict__ cr,
                                          const float* __restrict__ q, int lane) {
    float part = 0.f;
#pragma unroll
    for (int d = lane; d < DD; d += 128) {
        float gi = ar[d] + br[d] + cb[d];
        float gfl = ar[DD + d] + br[DD + d] + cb[DD + d];
        float gfr = ar[2 * DD + d] + br[2 * DD + d] + cb[2 * DD + d];
        float gu = ar[3 * DD + d] + br[3 * DD + d] + cb[3 * DD + d];
        float go = ar[4 * DD + d] + br[4 * DD + d] + cb[4 * DD + d];
        float nc = cl[d] * sigm(gfl + 1.f) + cr[d] * sigm(gfr + 1.f) + tanhf(gu) * sigm(gi);
        part += sigm(go) * tanhf(nc) * q[d];
    }
#pragma unroll
    for (int off = 32; off; off >>= 1) part += __shfl_down(part, off);
    return part;
}

// gate pair
__device__ __forceinline__ void gate2n(const float* __restrict__ ar,
                                       const float* __restrict__ br,
                                       const float* __restrict__ cb,
                                       const float* __restrict__ cl,
                                       const float* __restrict__ cr, int d,
                                       float nh[2], float nc[2]) {
    float2 A0 = *(const float2*)(ar + d),          B0 = *(const float2*)(br + d);
    float2 A1 = *(const float2*)(ar + DD + d),     B1 = *(const float2*)(br + DD + d);
    float2 A2 = *(const float2*)(ar + 2 * DD + d), B2 = *(const float2*)(br + 2 * DD + d);
    float2 A3 = *(const float2*)(ar + 3 * DD + d), B3 = *(const float2*)(br + 3 * DD + d);
    float2 A4 = *(const float2*)(ar + 4 * DD + d), B4 = *(const float2*)(br + 4 * DD + d);
    float2 C0 = *(const float2*)(cb + d);
    float2 C1 = *(const float2*)(cb + DD + d);
    float2 C2 = *(const float2*)(cb + 2 * DD + d);
    float2 C3 = *(const float2*)(cb + 3 * DD + d);
    float2 C4 = *(const float2*)(cb + 4 * DD + d);
    float2 CL = *(const float2*)(cl + d);
    float2 CR = *(const float2*)(cr + d);
    float gi0 = A0.x + B0.x + C0.x, gi1 = A0.y + B0.y + C0.y;
    float gfl0 = A1.x + B1.x + C1.x, gfl1 = A1.y + B1.y + C1.y;
    float gfr0 = A2.x + B2.x + C2.x, gfr1 = A2.y + B2.y + C2.y;
    float gu0 = A3.x + B3.x + C3.x, gu1 = A3.y + B3.y + C3.y;
    float go0 = A4.x + B4.x + C4.x, go1 = A4.y + B4.y + C4.y;
    nc[0] = CL.x * sigm(gfl0 + 1.f) + CR.x * sigm(gfr0 + 1.f) + tanhf(gu0) * sigm(gi0);
    nc[1] = CL.y * sigm(gfl1 + 1.f) + CR.y * sigm(gfr1 + 1.f) + tanhf(gu1) * sigm(gi1);
    nh[0] = sigm(go0) * tanhf(nc[0]);
    nh[1] = sigm(go1) * tanhf(nc[1]);
}

// ---------------------------------------------------------------------------
// initial scores: grid (12, 64)
// ---------------------------------------------------------------------------
__global__ __launch_bounds__(256) void scoreall_k(const float* __restrict__ acache,
                                                  const float* __restrict__ bcache,
                                                  const float* __restrict__ cbuf,
                                                  const float* __restrict__ compb,
                                                  const float* __restrict__ q,
                                                  float* __restrict__ scores_g) {
    __shared__ float red_s[4];
    const int tid = threadIdx.x;
    const int b = blockIdx.y;
    const int p = blockIdx.x * 2 + (tid >> 7);
    const bool valid = p < NSTEP;
    float w = 0.f;
    if (valid) {
        w = half_dot(acache + (size_t)(b * LL + p) * GG,
                     bcache + (size_t)(b * LL + p + 1) * GG, compb,
                     cbuf + (size_t)(b * LL + p) * DD,
                     cbuf + (size_t)(b * LL + p + 1) * DD, q, tid & 127);
    }
    if ((tid & 63) == 0) red_s[tid >> 6] = w;
    __syncthreads();
    if ((tid == 0 || tid == 128) && valid) {
        int base = tid >> 6;
        scores_g[b * NSTEP + p] = red_s[base] + red_s[base + 1];
    }
}

// ---------------------------------------------------------------------------
// stepA: 64 blocks (one per batch). rescore -> argmax -> merge -> hout (+bf16
// hi/lo split for the MFMA stepB) ; shift per-batch state (global).
// ---------------------------------------------------------------------------
__global__ __launch_bounds__(256) void stepA_k(
    int i, const int* __restrict__ length, float* __restrict__ cbuf,
    const float* __restrict__ acache, const float* __restrict__ bcache,
    float* __restrict__ hout, unsigned short* __restrict__ hh,
    unsigned short* __restrict__ hl, float* __restrict__ scores_g,
    int* __restrict__ seq_g, int* __restrict__ kp_g, int* __restrict__ msel,
    const float* __restrict__ compb, const float* __restrict__ q, float* __restrict__ out) {
    __shared__ float red_s[4];
    __shared__ float sc_l[32];
    __shared__ int seq_l[32];
    __shared__ int k_sh;
    const int tid = threadIdx.x;
    const int b = blockIdx.x;
    const int lane7 = tid & 127;
    const int lenb = length[b];
    const int ncand = NSTEP - i;

    if (i == 0) {
        if (tid < LL) seq_l[tid] = tid;
    } else {
        if (tid < LL - i) seq_l[tid] = seq_g[b * 32 + tid];
    }
    if (tid < ncand) sc_l[tid] = scores_g[b * NSTEP + tid];
    __syncthreads();
    const int kp = (i > 0) ? kp_g[b] : 0;

    if (i > 0 && i < lenb) {  // rescore candidates kp-1, kp (half-block each)
        int p = (tid < 128) ? (kp - 1) : kp;
        bool valid = (p >= 0) && (p < ncand);
        float w = 0.f;
        if (valid) {
            int sl = seq_l[p], sr = seq_l[p + 1];
            const float* ar = acache + (size_t)(b * LL + sl) * GG;
            const float* br = bcache + (size_t)(b * LL + sr) * GG;
            const float* cl = cbuf + (size_t)(b * LL + sl) * DD;
            const float* cr = cbuf + (size_t)(b * LL + sr) * DD;
#pragma unroll
            for (int pass = 0; pass < 2; ++pass) {
                int d = pass * 256 + lane7 * 2;
                float nh[2], nc[2];
                gate2n(ar, br, compb, cl, cr, d, nh, nc);
                float2 Q = *(const float2*)(q + d);
                w += nh[0] * Q.x + nh[1] * Q.y;
            }
#pragma unroll
            for (int off = 32; off; off >>= 1) w += __shfl_down(w, off);
        }
        if ((tid & 63) == 0) red_s[tid >> 6] = w;
        __syncthreads();
        if (tid == 0) {
            if (kp - 1 >= 0) sc_l[kp - 1] = red_s[0] + red_s[1];
            if (kp < ncand) sc_l[kp] = red_s[2] + red_s[3];
        }
        __syncthreads();
    }

    if (i + 1 < lenb) {
        if (tid == 0) {
            const int vmax = lenb - i - 2;
            int k = 0;
            float best = sc_l[0];
            for (int pp = 1; pp <= vmax; ++pp)
                if (sc_l[pp] > best) { best = sc_l[pp]; k = pp; }
            k_sh = k;
        }
        __syncthreads();
        const int k = k_sh;
        const int sl = seq_l[k], sr = seq_l[k + 1];
        const float* ar = acache + (size_t)(b * LL + sl) * GG;
        const float* br = bcache + (size_t)(b * LL + sr) * GG;
        const float* cl = cbuf + (size_t)(b * LL + sl) * DD;
        const float* cr = cbuf + (size_t)(b * LL + sr) * DD;
        {
            const int d = 2 * tid;
            float nh[2], nc[2];
            gate2n(ar, br, compb, cl, cr, d, nh, nc);
            *(float2*)(cbuf + (size_t)(b * LL + sl) * DD + d) = make_float2(nc[0], nc[1]);
            *(float2*)(hout + (size_t)b * DD + d) = make_float2(nh[0], nh[1]);
            // bf16 hi/lo split for stepB's MFMA A-operand
            ushort2 hv, lv;
            hv.x = f2bf(nh[0]); lv.x = f2bf(nh[0] - bf2f(hv.x));
            hv.y = f2bf(nh[1]); lv.y = f2bf(nh[1] - bf2f(hv.y));
            *(ushort2*)(hh + (size_t)b * DD + d) = hv;
            *(ushort2*)(hl + (size_t)b * DD + d) = lv;
            if (i == NSTEP - 1)
                *(float2*)(out + (size_t)b * DD + d) = make_float2(nh[0], nh[1]);
        }
        float sv = (tid + 1 < ncand) ? sc_l[tid + 1] : 0.f;
        int qv = (tid + 1 < LL - i) ? seq_l[tid + 1] : 0;
        __syncthreads();
        if (tid >= k + 1 && tid <= ncand - 2) sc_l[tid] = sv;
        if (tid >= k + 1 && tid <= LL - i - 2) seq_l[tid] = qv;
        if (tid < ncand - 1) scores_g[b * NSTEP + tid] = sc_l[tid];
        if (tid < LL - i - 1) seq_g[b * 32 + tid] = seq_l[tid];
        if (tid == 0) { kp_g[b] = k; msel[b] = sl; }
    } else if (i == NSTEP - 1) {
        const int d = 2 * tid;
        *(float2*)(out + (size_t)b * DD + d) = *(const float2*)(hout + (size_t)b * DD + d);
    }
}

// ---------------------------------------------------------------------------
// stepB via bf16x3 MFMA: O[m][n] = sum_k hout[m][k]*W[n][k], M=64, N=32/block,
// K=512. 4 waves: wave w owns m-tiles {2*(w>>1), 2*(w>>1)+1} x n-tile (w&1).
// ---------------------------------------------------------------------------
__global__ __launch_bounds__(256) void stepB_mfma(
    const unsigned short* __restrict__ hh, const unsigned short* __restrict__ hl,
    const int* __restrict__ msel,
    const unsigned short* __restrict__ Wh, const unsigned short* __restrict__ Wl,
    float* __restrict__ acache, float* __restrict__ bcache) {
    __shared__ int msel_s[BB];
    const int tid = threadIdx.x;
    const int bid = blockIdx.x;
    if (tid < BB) msel_s[tid] = msel[tid];
    __syncthreads();

    const int w = tid >> 6, lane = tid & 63;
    const int mt0 = (w >> 1) * 2;           // this wave's first m-tile
    const int nt = w & 1;                   // this wave's n-tile
    const int lr = lane & 15;
    const int kg = lane >> 4;               // k-group (8 contiguous k)
    const int n = bid * 32 + nt * 16 + lr;  // global output column

    const unsigned short* wh_row = Wh + (size_t)n * DD;
    const unsigned short* wl_row = Wl + (size_t)n * DD;
    const unsigned short* a0h_row = hh + (size_t)(mt0 * 16 + lr) * DD;
    const unsigned short* a0l_row = hl + (size_t)(mt0 * 16 + lr) * DD;
    const unsigned short* a1h_row = a0h_row + 16 * DD;
    const unsigned short* a1l_row = a0l_row + 16 * DD;

    f32x4 acc0 = {0.f, 0.f, 0.f, 0.f};
    f32x4 acc1 = {0.f, 0.f, 0.f, 0.f};

#pragma unroll 4
    for (int ks = 0; ks < 16; ++ks) {
        const int kb = ks * 32 + kg * 8;
        short8 bh = *(const short8*)(wh_row + kb);
        short8 bl = *(const short8*)(wl_row + kb);
        short8 a0h = *(const short8*)(a0h_row + kb);
        short8 a0l = *(const short8*)(a0l_row + kb);
        short8 a1h = *(const short8*)(a1h_row + kb);
        short8 a1l = *(const short8*)(a1l_row + kb);
        acc0 = __builtin_amdgcn_mfma_f32_16x16x32_bf16(a0h, bh, acc0, 0, 0, 0);
        acc1 = __builtin_amdgcn_mfma_f32_16x16x32_bf16(a1h, bh, acc1, 0, 0, 0);
        acc0 = __builtin_amdgcn_mfma_f32_16x16x32_bf16(a0l, bh, acc0, 0, 0, 0);
        acc1 = __builtin_amdgcn_mfma_f32_16x16x32_bf16(a1l, bh, acc1, 0, 0, 0);
        acc0 = __builtin_amdgcn_mfma_f32_16x16x32_bf16(a0h, bl, acc0, 0, 0, 0);
        acc1 = __builtin_amdgcn_mfma_f32_16x16x32_bf16(a1h, bl, acc1, 0, 0, 0);
    }

    // write: n fixed per lane; rows m = mt*16 + kg*4 + r, scattered by msel
#pragma unroll
    for (int t = 0; t < 2; ++t) {
        f32x4 acc = t ? acc1 : acc0;
        const int mbase = (mt0 + t) * 16 + kg * 4;
#pragma unroll
        for (int r = 0; r < 4; ++r) {
            int m = mbase + r;
            size_t row = (size_t)(m * LL + msel_s[m]);
            float* dst = (n < GG) ? (acache + row * GG + n)
                                  : (bcache + row * GG + (n - GG));
            *dst = acc[r];
        }
    }
}

// ---------------------------------------------------------------------------
extern "C" void kernel_launch(void* const* d_in, const int* in_sizes, int n_in, void* d_out,
                              int out_size, void* d_ws, size_t ws_size, hipStream_t stream) {
    const float* inp = (const float*)d_in[0];
    const int* length = (const int*)d_in[1];
    const float* word_W = (const float*)d_in[2];
    const float* word_b = (const float*)d_in[3];
    const float* comp_W = (const float*)d_in[4];
    const float* comp_b = (const float*)d_in[5];
    const float* comp_q = (const float*)d_in[6];
    float* out = (float*)d_out;

    float* ws = (float*)d_ws;
    size_t off = 0;
    float* cbuf = ws + off;   off += (size_t)BB * LL * DD;
    float* acache = ws + off; off += (size_t)BB * LL * GG;
    float* bcache = ws + off; off += (size_t)BB * LL * GG;
    float* hout = ws + off;   off += (size_t)BB * DD;
    float* scores = ws + off; off += 2048;
    int* seq_g = (int*)(ws + off); off += BB * 32;
    int* kp_g = (int*)(ws + off);  off += 64;
    int* msel = (int*)(ws + off);  off += 64;
    unsigned short* Wh = (unsigned short*)(ws + off); off += (size_t)5120 * DD / 2;
    unsigned short* Wl = (unsigned short*)(ws + off); off += (size_t)5120 * DD / 2;
    unsigned short* hh = (unsigned short*)(ws + off); off += (size_t)BB * DD / 2;
    unsigned short* hl = (unsigned short*)(ws + off); off += (size_t)BB * DD / 2;
    unsigned short* Ah = (unsigned short*)(ws + off); off += (size_t)BB * LL * DD / 2;
    unsigned short* Al = (unsigned short*)(ws + off); off += (size_t)BB * LL * DD / 2;
    (void)ws_size; (void)in_sizes; (void)n_in; (void)out_size;

    // one-time bf16 hi/lo split of comp_W (rearranged [5120][512])
    splitW_k<<<2560, 256, 0, stream>>>(comp_W, Wh, Wl);

    // word projection: h (bf16 hi/lo), c (fp32) = split(inp @ word_W.T + word_b)
    gemm64w<<<dim3(8, 24), 256, 0, stream>>>(inp, word_W, word_b, Ah, Al, cbuf);

    // a/b caches for all 1536 items via bf16x3 MFMA (v2: 960 blocks, dbuf)
    gemm_big_mfma<<<960, 256, 0, stream>>>(Ah, Al, Wh, Wl, acache, bcache);

    // initial candidate scores
    scoreall_k<<<dim3(12, 64), 256, 0, stream>>>(acache, bcache, cbuf, comp_b, comp_q, scores);

    // 23 merge steps: A (select+merge) then B (bf16x3 MFMA GEMM for merged rows)
    for (int i = 0; i < NSTEP; ++i) {
        stepA_k<<<BB, 256, 0, stream>>>(i, length, cbuf, acache, bcache, hout, hh, hl,
                                        scores, seq_g, kp_g, msel, comp_b, comp_q, out);
        if (i < NSTEP - 1) {
            stepB_mfma<<<NTILES, 256, 0, stream>>>(hh, hl, msel, Wh, Wl, acache, bcache);
        }
    }
}

// Round 6
// 625.178 us; speedup vs baseline: 3.0815x; 1.0990x over previous
//
#include <hip/hip_runtime.h>
#include <math.h>

// Problem constants
#define BB 64
#define LL 24
#define DD 512
#define GG 2560        // 5*H
#define NSTEP 23       // LL-1
#define NTILES 160     // stepB n-tiles: 5120/32

__device__ __forceinline__ float sigm(float x) { return 1.0f / (1.0f + __expf(-x)); }

// bf16 split helpers (RNE)
__device__ __forceinline__ unsigned short f2bf(float x) {
    unsigned u = __float_as_uint(x);
    unsigned r = (u + 0x7fff + ((u >> 16) & 1)) >> 16;
    return (unsigned short)r;
}
__device__ __forceinline__ float bf2f(unsigned short b) {
    return __uint_as_float(((unsigned)b) << 16);
}

using short8 = __attribute__((ext_vector_type(8))) short;
using f32x4 = __attribute__((ext_vector_type(4))) float;

// ---------------------------------------------------------------------------
// one-time: split comp_W into bf16 hi/lo, rearranged to [5120][512]
// row n (<2560): comp_W[n][0:512] (a-part); row n>=2560: comp_W[n-2560][512:1024]
// ---------------------------------------------------------------------------
__global__ __launch_bounds__(256) void splitW_k(const float* __restrict__ comp_W,
                                                unsigned short* __restrict__ Wh,
                                                unsigned short* __restrict__ Wl) {
    int t = (blockIdx.x * 256 + threadIdx.x) * 4;   // 5120*512 elems, 4/thread
    int n = t >> 9;
    int k = t & 511;
    const float* src = (n < GG) ? (comp_W + (size_t)n * (2 * DD) + k)
                                : (comp_W + (size_t)(n - GG) * (2 * DD) + DD + k);
    float4 v = *(const float4*)src;
    ushort4 h, l;
    h.x = f2bf(v.x); l.x = f2bf(v.x - bf2f(h.x));
    h.y = f2bf(v.y); l.y = f2bf(v.y - bf2f(h.y));
    h.z = f2bf(v.z); l.z = f2bf(v.z - bf2f(h.z));
    h.w = f2bf(v.w); l.w = f2bf(v.w - bf2f(h.w));
    *(ushort4*)(Wh + t) = h;
    *(ushort4*)(Wl + t) = l;
}

// ---------------------------------------------------------------------------
// fp32 GEMM, 64x128 tile — word projection. h-part (n<512) is written as
// bf16 hi/lo (MFMA A-operand for gemm_big_mfma); c-part (n>=512) stays fp32.
// (round-0 verified numerics)
// ---------------------------------------------------------------------------
__global__ __launch_bounds__(256) void gemm64w(const float* __restrict__ A,
                                               const float* __restrict__ Wt,
                                               const float* __restrict__ bias,
                                               unsigned short* __restrict__ Ah,
                                               unsigned short* __restrict__ Al,
                                               float* __restrict__ O1) {
    __shared__ float As[16][68];
    __shared__ float Bs[16][132];
    const int tid = threadIdx.x;
    const int n0 = blockIdx.x * 128;
    const int m0 = blockIdx.y * 64;
    const int tn = tid & 15;
    const int tm = tid >> 4;

    float acc[4][8];
#pragma unroll
    for (int y = 0; y < 4; ++y)
#pragma unroll
        for (int x = 0; x < 8; ++x) acc[y][x] = 0.f;

    for (int kt = 0; kt < 512; kt += 16) {
        {
            int r = tid >> 2, c4 = tid & 3;
            float4 v = *(const float4*)(A + (size_t)(m0 + r) * DD + kt + c4 * 4);
            As[c4 * 4 + 0][r] = v.x;
            As[c4 * 4 + 1][r] = v.y;
            As[c4 * 4 + 2][r] = v.z;
            As[c4 * 4 + 3][r] = v.w;
        }
#pragma unroll
        for (int ii = 0; ii < 2; ++ii) {
            int idx = tid + ii * 256;
            int r = idx >> 2, c4 = idx & 3;
            float4 v = *(const float4*)(Wt + (size_t)(n0 + r) * DD + kt + c4 * 4);
            Bs[c4 * 4 + 0][r] = v.x;
            Bs[c4 * 4 + 1][r] = v.y;
            Bs[c4 * 4 + 2][r] = v.z;
            Bs[c4 * 4 + 3][r] = v.w;
        }
        __syncthreads();
#pragma unroll
        for (int k = 0; k < 16; ++k) {
            float4 a = *(const float4*)&As[k][tm * 4];
            float4 b0 = *(const float4*)&Bs[k][tn * 4];
            float4 b1 = *(const float4*)&Bs[k][64 + tn * 4];
            float av[4] = {a.x, a.y, a.z, a.w};
            float bv[8] = {b0.x, b0.y, b0.z, b0.w, b1.x, b1.y, b1.z, b1.w};
#pragma unroll
            for (int y = 0; y < 4; ++y)
#pragma unroll
                for (int x = 0; x < 8; ++x) acc[y][x] += av[y] * bv[x];
        }
        __syncthreads();
    }

#pragma unroll
    for (int y = 0; y < 4; ++y) {
        const int m = m0 + tm * 4 + y;
#pragma unroll
        for (int g = 0; g < 2; ++g) {
            int n = n0 + g * 64 + tn * 4;
            float4 v;
            v.x = acc[y][g * 4 + 0] + bias[n + 0];
            v.y = acc[y][g * 4 + 1] + bias[n + 1];
            v.z = acc[y][g * 4 + 2] + bias[n + 2];
            v.w = acc[y][g * 4 + 3] + bias[n + 3];
            if (n < DD) {
                ushort4 hv, lv;
                hv.x = f2bf(v.x); lv.x = f2bf(v.x - bf2f(hv.x));
                hv.y = f2bf(v.y); lv.y = f2bf(v.y - bf2f(hv.y));
                hv.z = f2bf(v.z); lv.z = f2bf(v.z - bf2f(hv.z));
                hv.w = f2bf(v.w); lv.w = f2bf(v.w - bf2f(hv.w));
                *(ushort4*)(Ah + (size_t)m * DD + n) = hv;
                *(ushort4*)(Al + (size_t)m * DD + n) = lv;
            } else {
                *(float4*)(O1 + (size_t)m * DD + (n - DD)) = v;
            }
        }
    }
}

// ---------------------------------------------------------------------------
// gemm_big_mfma v3: LDS-staged bf16x3 MFMA GEMM. M=1536, N=5120, K=512.
// 480 blocks (128x128 tile), 4 waves 2x2 (wave = 64x64 = 4x4 16-tiles).
// BK=64 K-tiles reg-prefetched (T14 split) into padded LDS [128][72] bf16
// (144 B rows: 16B-aligned b128, 2-way-max bank aliasing = free).
// Each operand byte fetched from global ONCE per block (r3 fetched 2x).
// XCD n-panel swizzle: each XCD's 60 blocks share a 1.3 MB B-slice + 3.1 MB A
// -> L2-resident. Fragment/C-D layouts identical to verified r3.
// ---------------------------------------------------------------------------
__global__ __launch_bounds__(256) void gemm_big_mfma(
    const unsigned short* __restrict__ Ah, const unsigned short* __restrict__ Al,
    const unsigned short* __restrict__ Wh, const unsigned short* __restrict__ Wl,
    float* __restrict__ O0, float* __restrict__ O1) {
    __shared__ unsigned short AhS[128][72];
    __shared__ unsigned short AlS[128][72];
    __shared__ unsigned short BhS[128][72];
    __shared__ unsigned short BlS[128][72];

    const int tid = threadIdx.x;
    // XCD swizzle (480 = 8*60, bijective): xcd j owns n-panels [5j,5j+5) x all m
    const int xcd = blockIdx.x & 7, idx = blockIdx.x >> 3;
    const int n0 = (xcd * 5 + idx % 5) * 128;
    const int m0 = (idx / 5) * 128;

    const int w = tid >> 6, lane = tid & 63;
    const int mq = w >> 1, nq = w & 1;
    const int lr = lane & 15, kg = lane >> 4;

    // staging: thread handles chunks c = tid + it*256; row = c>>3, k8 = c&7
    const int srow = tid >> 3;   // + it*32
    const int sk8 = tid & 7;

    const unsigned short* agh = Ah + (size_t)(m0 + srow) * DD + sk8 * 8;
    const unsigned short* agl = Al + (size_t)(m0 + srow) * DD + sk8 * 8;
    const unsigned short* bgh = Wh + (size_t)(n0 + srow) * DD + sk8 * 8;
    const unsigned short* bgl = Wl + (size_t)(n0 + srow) * DD + sk8 * 8;

    f32x4 acc[4][4];
#pragma unroll
    for (int mt = 0; mt < 4; ++mt)
#pragma unroll
        for (int nt = 0; nt < 4; ++nt) acc[mt][nt] = (f32x4){0.f, 0.f, 0.f, 0.f};

    short8 rAh[4], rAl[4], rBh[4], rBl[4];

#define LOADT(kt)                                                            \
    {                                                                        \
        _Pragma("unroll")                                                    \
        for (int it = 0; it < 4; ++it) {                                     \
            const size_t ro = (size_t)it * 32 * DD + (kt);                   \
            rAh[it] = *(const short8*)(agh + ro);                            \
            rAl[it] = *(const short8*)(agl + ro);                            \
            rBh[it] = *(const short8*)(bgh + ro);                            \
            rBl[it] = *(const short8*)(bgl + ro);                            \
        }                                                                    \
    }
#define WRITET()                                                             \
    {                                                                        \
        _Pragma("unroll")                                                    \
        for (int it = 0; it < 4; ++it) {                                     \
            const int row = srow + it * 32;                                  \
            *(short8*)&AhS[row][sk8 * 8] = rAh[it];                          \
            *(short8*)&AlS[row][sk8 * 8] = rAl[it];                          \
            *(short8*)&BhS[row][sk8 * 8] = rBh[it];                          \
            *(short8*)&BlS[row][sk8 * 8] = rBl[it];                          \
        }                                                                    \
    }

    LOADT(0);
    WRITET();
    __syncthreads();

    for (int kti = 0; kti < 8; ++kti) {
        if (kti + 1 < 8) LOADT((kti + 1) * 64);   // issue early: hides under compute
#pragma unroll
        for (int ks2 = 0; ks2 < 2; ++ks2) {
            const int kb = ks2 * 32 + kg * 8;
            short8 fah[4], fal[4], fbh[4], fbl[4];
#pragma unroll
            for (int t = 0; t < 4; ++t) {
                fah[t] = *(const short8*)&AhS[mq * 64 + t * 16 + lr][kb];
                fal[t] = *(const short8*)&AlS[mq * 64 + t * 16 + lr][kb];
                fbh[t] = *(const short8*)&BhS[nq * 64 + t * 16 + lr][kb];
                fbl[t] = *(const short8*)&BlS[nq * 64 + t * 16 + lr][kb];
            }
#pragma unroll
            for (int mt = 0; mt < 4; ++mt)
#pragma unroll
                for (int nt = 0; nt < 4; ++nt) {
                    acc[mt][nt] = __builtin_amdgcn_mfma_f32_16x16x32_bf16(fal[mt], fbh[nt], acc[mt][nt], 0, 0, 0);
                    acc[mt][nt] = __builtin_amdgcn_mfma_f32_16x16x32_bf16(fah[mt], fbl[nt], acc[mt][nt], 0, 0, 0);
                    acc[mt][nt] = __builtin_amdgcn_mfma_f32_16x16x32_bf16(fah[mt], fbh[nt], acc[mt][nt], 0, 0, 0);
                }
        }
        __syncthreads();               // all waves done reading this tile
        if (kti + 1 < 8) {
            WRITET();                  // commit prefetched tile
            __syncthreads();
        }
    }
#undef LOADT
#undef WRITET

    // C/D layout: col = lane&15, row = (lane>>4)*4 + reg   [verified]
#pragma unroll
    for (int mt = 0; mt < 4; ++mt) {
        const int mbase = m0 + mq * 64 + mt * 16 + kg * 4;
#pragma unroll
        for (int nt = 0; nt < 4; ++nt) {
            const int n = n0 + nq * 64 + nt * 16 + lr;
#pragma unroll
            for (int r = 0; r < 4; ++r) {
                const int m = mbase + r;
                float* dst = (n < GG) ? (O0 + (size_t)m * GG + n)
                                      : (O1 + (size_t)m * GG + (n - GG));
                *dst = acc[mt][nt][r];
            }
        }
    }
}

// ---------------------------------------------------------------------------
// half-block (128-lane) candidate scorer
// ---------------------------------------------------------------------------
__device__ __forceinline__ float half_dot(const float* __restrict__ ar,
                                          const float* __restrict__ br,
                                          const float* __restrict__ cb,
                                          const float* __restrict__ cl,
                                          const float* __restrict__ cr,
                                          const float* __restrict__ q, int lane) {
    float part = 0.f;
#pragma unroll
    for (int d = lane; d < DD; d += 128) {
        float gi = ar[d] + br[d] + cb[d];
        float gfl = ar[DD + d] + br[DD + d] + cb[DD + d];
        float gfr = ar[2 * DD + d] + br[2 * DD + d] + cb[2 * DD + d];
        float gu = ar[3 * DD + d] + br[3 * DD + d] + cb[3 * DD + d];
        float go = ar[4 * DD + d] + br[4 * DD + d] + cb[4 * DD + d];
        float nc = cl[d] * sigm(gfl + 1.f) + cr[d] * sigm(gfr + 1.f) + tanhf(gu) * sigm(gi);
        part += sigm(go) * tanhf(nc) * q[d];
    }
#pragma unroll
    for (int off = 32; off; off >>= 1) part += __shfl_down(part, off);
    return part;
}

// gate pair
__device__ __forceinline__ void gate2n(const float* __restrict__ ar,
                                       const float* __restrict__ br,
                                       const float* __restrict__ cb,
                                       const float* __restrict__ cl,
                                       const float* __restrict__ cr, int d,
                                       float nh[2], float nc[2]) {
    float2 A0 = *(const float2*)(ar + d),          B0 = *(const float2*)(br + d);
    float2 A1 = *(const float2*)(ar + DD + d),     B1 = *(const float2*)(br + DD + d);
    float2 A2 = *(const float2*)(ar + 2 * DD + d), B2 = *(const float2*)(br + 2 * DD + d);
    float2 A3 = *(const float2*)(ar + 3 * DD + d), B3 = *(const float2*)(br + 3 * DD + d);
    float2 A4 = *(const float2*)(ar + 4 * DD + d), B4 = *(const float2*)(br + 4 * DD + d);
    float2 C0 = *(const float2*)(cb + d);
    float2 C1 = *(const float2*)(cb + DD + d);
    float2 C2 = *(const float2*)(cb + 2 * DD + d);
    float2 C3 = *(const float2*)(cb + 3 * DD + d);
    float2 C4 = *(const float2*)(cb + 4 * DD + d);
    float2 CL = *(const float2*)(cl + d);
    float2 CR = *(const float2*)(cr + d);
    float gi0 = A0.x + B0.x + C0.x, gi1 = A0.y + B0.y + C0.y;
    float gfl0 = A1.x + B1.x + C1.x, gfl1 = A1.y + B1.y + C1.y;
    float gfr0 = A2.x + B2.x + C2.x, gfr1 = A2.y + B2.y + C2.y;
    float gu0 = A3.x + B3.x + C3.x, gu1 = A3.y + B3.y + C3.y;
    float go0 = A4.x + B4.x + C4.x, go1 = A4.y + B4.y + C4.y;
    nc[0] = CL.x * sigm(gfl0 + 1.f) + CR.x * sigm(gfr0 + 1.f) + tanhf(gu0) * sigm(gi0);
    nc[1] = CL.y * sigm(gfl1 + 1.f) + CR.y * sigm(gfr1 + 1.f) + tanhf(gu1) * sigm(gi1);
    nh[0] = sigm(go0) * tanhf(nc[0]);
    nh[1] = sigm(go1) * tanhf(nc[1]);
}

// ---------------------------------------------------------------------------
// initial scores: grid (12, 64)
// ---------------------------------------------------------------------------
__global__ __launch_bounds__(256) void scoreall_k(const float* __restrict__ acache,
                                                  const float* __restrict__ bcache,
                                                  const float* __restrict__ cbuf,
                                                  const float* __restrict__ compb,
                                                  const float* __restrict__ q,
                                                  float* __restrict__ scores_g) {
    __shared__ float red_s[4];
    const int tid = threadIdx.x;
    const int b = blockIdx.y;
    const int p = blockIdx.x * 2 + (tid >> 7);
    const bool valid = p < NSTEP;
    float w = 0.f;
    if (valid) {
        w = half_dot(acache + (size_t)(b * LL + p) * GG,
                     bcache + (size_t)(b * LL + p + 1) * GG, compb,
                     cbuf + (size_t)(b * LL + p) * DD,
                     cbuf + (size_t)(b * LL + p + 1) * DD, q, tid & 127);
    }
    if ((tid & 63) == 0) red_s[tid >> 6] = w;
    __syncthreads();
    if ((tid == 0 || tid == 128) && valid) {
        int base = tid >> 6;
        scores_g[b * NSTEP + p] = red_s[base] + red_s[base + 1];
    }
}

// ---------------------------------------------------------------------------
// stepA: 64 blocks (one per batch). rescore -> argmax -> merge -> hout (+bf16
// hi/lo split for the MFMA stepB) ; shift per-batch state (global).
// ---------------------------------------------------------------------------
__global__ __launch_bounds__(256) void stepA_k(
    int i, const int* __restrict__ length, float* __restrict__ cbuf,
    const float* __restrict__ acache, const float* __restrict__ bcache,
    float* __restrict__ hout, unsigned short* __restrict__ hh,
    unsigned short* __restrict__ hl, float* __restrict__ scores_g,
    int* __restrict__ seq_g, int* __restrict__ kp_g, int* __restrict__ msel,
    const float* __restrict__ compb, const float* __restrict__ q, float* __restrict__ out) {
    __shared__ float red_s[4];
    __shared__ float sc_l[32];
    __shared__ int seq_l[32];
    __shared__ int k_sh;
    const int tid = threadIdx.x;
    const int b = blockIdx.x;
    const int lane7 = tid & 127;
    const int lenb = length[b];
    const int ncand = NSTEP - i;

    if (i == 0) {
        if (tid < LL) seq_l[tid] = tid;
    } else {
        if (tid < LL - i) seq_l[tid] = seq_g[b * 32 + tid];
    }
    if (tid < ncand) sc_l[tid] = scores_g[b * NSTEP + tid];
    __syncthreads();
    const int kp = (i > 0) ? kp_g[b] : 0;

    if (i > 0 && i < lenb) {  // rescore candidates kp-1, kp (half-block each)
        int p = (tid < 128) ? (kp - 1) : kp;
        bool valid = (p >= 0) && (p < ncand);
        float w = 0.f;
        if (valid) {
            int sl = seq_l[p], sr = seq_l[p + 1];
            const float* ar = acache + (size_t)(b * LL + sl) * GG;
            const float* br = bcache + (size_t)(b * LL + sr) * GG;
            const float* cl = cbuf + (size_t)(b * LL + sl) * DD;
            const float* cr = cbuf + (size_t)(b * LL + sr) * DD;
#pragma unroll
            for (int pass = 0; pass < 2; ++pass) {
                int d = pass * 256 + lane7 * 2;
                float nh[2], nc[2];
                gate2n(ar, br, compb, cl, cr, d, nh, nc);
                float2 Q = *(const float2*)(q + d);
                w += nh[0] * Q.x + nh[1] * Q.y;
            }
#pragma unroll
            for (int off = 32; off; off >>= 1) w += __shfl_down(w, off);
        }
        if ((tid & 63) == 0) red_s[tid >> 6] = w;
        __syncthreads();
        if (tid == 0) {
            if (kp - 1 >= 0) sc_l[kp - 1] = red_s[0] + red_s[1];
            if (kp < ncand) sc_l[kp] = red_s[2] + red_s[3];
        }
        __syncthreads();
    }

    if (i + 1 < lenb) {
        if (tid == 0) {
            const int vmax = lenb - i - 2;
            int k = 0;
            float best = sc_l[0];
            for (int pp = 1; pp <= vmax; ++pp)
                if (sc_l[pp] > best) { best = sc_l[pp]; k = pp; }
            k_sh = k;
        }
        __syncthreads();
        const int k = k_sh;
        const int sl = seq_l[k], sr = seq_l[k + 1];
        const float* ar = acache + (size_t)(b * LL + sl) * GG;
        const float* br = bcache + (size_t)(b * LL + sr) * GG;
        const float* cl = cbuf + (size_t)(b * LL + sl) * DD;
        const float* cr = cbuf + (size_t)(b * LL + sr) * DD;
        {
            const int d = 2 * tid;
            float nh[2], nc[2];
            gate2n(ar, br, compb, cl, cr, d, nh, nc);
            *(float2*)(cbuf + (size_t)(b * LL + sl) * DD + d) = make_float2(nc[0], nc[1]);
            *(float2*)(hout + (size_t)b * DD + d) = make_float2(nh[0], nh[1]);
            // bf16 hi/lo split for stepB's MFMA A-operand
            ushort2 hv, lv;
            hv.x = f2bf(nh[0]); lv.x = f2bf(nh[0] - bf2f(hv.x));
            hv.y = f2bf(nh[1]); lv.y = f2bf(nh[1] - bf2f(hv.y));
            *(ushort2*)(hh + (size_t)b * DD + d) = hv;
            *(ushort2*)(hl + (size_t)b * DD + d) = lv;
            if (i == NSTEP - 1)
                *(float2*)(out + (size_t)b * DD + d) = make_float2(nh[0], nh[1]);
        }
        float sv = (tid + 1 < ncand) ? sc_l[tid + 1] : 0.f;
        int qv = (tid + 1 < LL - i) ? seq_l[tid + 1] : 0;
        __syncthreads();
        if (tid >= k + 1 && tid <= ncand - 2) sc_l[tid] = sv;
        if (tid >= k + 1 && tid <= LL - i - 2) seq_l[tid] = qv;
        if (tid < ncand - 1) scores_g[b * NSTEP + tid] = sc_l[tid];
        if (tid < LL - i - 1) seq_g[b * 32 + tid] = seq_l[tid];
        if (tid == 0) { kp_g[b] = k; msel[b] = sl; }
    } else if (i == NSTEP - 1) {
        const int d = 2 * tid;
        *(float2*)(out + (size_t)b * DD + d) = *(const float2*)(hout + (size_t)b * DD + d);
    }
}

// ---------------------------------------------------------------------------
// stepB via bf16x3 MFMA: O[m][n] = sum_k hout[m][k]*W[n][k], M=64, N=32/block,
// K=512. 4 waves: wave w owns m-tiles {2*(w>>1), 2*(w>>1)+1} x n-tile (w&1).
// ---------------------------------------------------------------------------
__global__ __launch_bounds__(256) void stepB_mfma(
    const unsigned short* __restrict__ hh, const unsigned short* __restrict__ hl,
    const int* __restrict__ msel,
    const unsigned short* __restrict__ Wh, const unsigned short* __restrict__ Wl,
    float* __restrict__ acache, float* __restrict__ bcache) {
    __shared__ int msel_s[BB];
    const int tid = threadIdx.x;
    const int bid = blockIdx.x;
    if (tid < BB) msel_s[tid] = msel[tid];
    __syncthreads();

    const int w = tid >> 6, lane = tid & 63;
    const int mt0 = (w >> 1) * 2;           // this wave's first m-tile
    const int nt = w & 1;                   // this wave's n-tile
    const int lr = lane & 15;
    const int kg = lane >> 4;               // k-group (8 contiguous k)
    const int n = bid * 32 + nt * 16 + lr;  // global output column

    const unsigned short* wh_row = Wh + (size_t)n * DD;
    const unsigned short* wl_row = Wl + (size_t)n * DD;
    const unsigned short* a0h_row = hh + (size_t)(mt0 * 16 + lr) * DD;
    const unsigned short* a0l_row = hl + (size_t)(mt0 * 16 + lr) * DD;
    const unsigned short* a1h_row = a0h_row + 16 * DD;
    const unsigned short* a1l_row = a0l_row + 16 * DD;

    f32x4 acc0 = {0.f, 0.f, 0.f, 0.f};
    f32x4 acc1 = {0.f, 0.f, 0.f, 0.f};

#pragma unroll 4
    for (int ks = 0; ks < 16; ++ks) {
        const int kb = ks * 32 + kg * 8;
        short8 bh = *(const short8*)(wh_row + kb);
        short8 bl = *(const short8*)(wl_row + kb);
        short8 a0h = *(const short8*)(a0h_row + kb);
        short8 a0l = *(const short8*)(a0l_row + kb);
        short8 a1h = *(const short8*)(a1h_row + kb);
        short8 a1l = *(const short8*)(a1l_row + kb);
        acc0 = __builtin_amdgcn_mfma_f32_16x16x32_bf16(a0h, bh, acc0, 0, 0, 0);
        acc1 = __builtin_amdgcn_mfma_f32_16x16x32_bf16(a1h, bh, acc1, 0, 0, 0);
        acc0 = __builtin_amdgcn_mfma_f32_16x16x32_bf16(a0l, bh, acc0, 0, 0, 0);
        acc1 = __builtin_amdgcn_mfma_f32_16x16x32_bf16(a1l, bh, acc1, 0, 0, 0);
        acc0 = __builtin_amdgcn_mfma_f32_16x16x32_bf16(a0h, bl, acc0, 0, 0, 0);
        acc1 = __builtin_amdgcn_mfma_f32_16x16x32_bf16(a1h, bl, acc1, 0, 0, 0);
    }

    // write: n fixed per lane; rows m = mt*16 + kg*4 + r, scattered by msel
#pragma unroll
    for (int t = 0; t < 2; ++t) {
        f32x4 acc = t ? acc1 : acc0;
        const int mbase = (mt0 + t) * 16 + kg * 4;
#pragma unroll
        for (int r = 0; r < 4; ++r) {
            int m = mbase + r;
            size_t row = (size_t)(m * LL + msel_s[m]);
            float* dst = (n < GG) ? (acache + row * GG + n)
                                  : (bcache + row * GG + (n - GG));
            *dst = acc[r];
        }
    }
}

// ---------------------------------------------------------------------------
extern "C" void kernel_launch(void* const* d_in, const int* in_sizes, int n_in, void* d_out,
                              int out_size, void* d_ws, size_t ws_size, hipStream_t stream) {
    const float* inp = (const float*)d_in[0];
    const int* length = (const int*)d_in[1];
    const float* word_W = (const float*)d_in[2];
    const float* word_b = (const float*)d_in[3];
    const float* comp_W = (const float*)d_in[4];
    const float* comp_b = (const float*)d_in[5];
    const float* comp_q = (const float*)d_in[6];
    float* out = (float*)d_out;

    float* ws = (float*)d_ws;
    size_t off = 0;
    float* cbuf = ws + off;   off += (size_t)BB * LL * DD;
    float* acache = ws + off; off += (size_t)BB * LL * GG;
    float* bcache = ws + off; off += (size_t)BB * LL * GG;
    float* hout = ws + off;   off += (size_t)BB * DD;
    float* scores = ws + off; off += 2048;
    int* seq_g = (int*)(ws + off); off += BB * 32;
    int* kp_g = (int*)(ws + off);  off += 64;
    int* msel = (int*)(ws + off);  off += 64;
    unsigned short* Wh = (unsigned short*)(ws + off); off += (size_t)5120 * DD / 2;
    unsigned short* Wl = (unsigned short*)(ws + off); off += (size_t)5120 * DD / 2;
    unsigned short* hh = (unsigned short*)(ws + off); off += (size_t)BB * DD / 2;
    unsigned short* hl = (unsigned short*)(ws + off); off += (size_t)BB * DD / 2;
    unsigned short* Ah = (unsigned short*)(ws + off); off += (size_t)BB * LL * DD / 2;
    unsigned short* Al = (unsigned short*)(ws + off); off += (size_t)BB * LL * DD / 2;
    (void)ws_size; (void)in_sizes; (void)n_in; (void)out_size;

    // one-time bf16 hi/lo split of comp_W (rearranged [5120][512])
    splitW_k<<<2560, 256, 0, stream>>>(comp_W, Wh, Wl);

    // word projection: h (bf16 hi/lo), c (fp32) = split(inp @ word_W.T + word_b)
    gemm64w<<<dim3(8, 24), 256, 0, stream>>>(inp, word_W, word_b, Ah, Al, cbuf);

    // a/b caches for all 1536 items via LDS-staged bf16x3 MFMA (v3)
    gemm_big_mfma<<<480, 256, 0, stream>>>(Ah, Al, Wh, Wl, acache, bcache);

    // initial candidate scores
    scoreall_k<<<dim3(12, 64), 256, 0, stream>>>(acache, bcache, cbuf, comp_b, comp_q, scores);

    // 23 merge steps: A (select+merge) then B (bf16x3 MFMA GEMM for merged rows)
    for (int i = 0; i < NSTEP; ++i) {
        stepA_k<<<BB, 256, 0, stream>>>(i, length, cbuf, acache, bcache, hout, hh, hl,
                                        scores, seq_g, kp_g, msel, comp_b, comp_q, out);
        if (i < NSTEP - 1) {
            stepB_mfma<<<NTILES, 256, 0, stream>>>(hh, hl, msel, Wh, Wl, acache, bcache);
        }
    }
}

// Round 7
// 585.229 us; speedup vs baseline: 3.2919x; 1.0683x over previous
//
#include <hip/hip_runtime.h>
#include <math.h>

// Problem constants
#define BB 64
#define LL 24
#define DD 512
#define GG 2560        // 5*H
#define NSTEP 23       // LL-1
#define NTILES 160     // stepB n-tiles: 5120/32

__device__ __forceinline__ float sigm(float x) { return 1.0f / (1.0f + __expf(-x)); }

// bf16 split helpers (RNE)
__device__ __forceinline__ unsigned short f2bf(float x) {
    unsigned u = __float_as_uint(x);
    unsigned r = (u + 0x7fff + ((u >> 16) & 1)) >> 16;
    return (unsigned short)r;
}
__device__ __forceinline__ float bf2f(unsigned short b) {
    return __uint_as_float(((unsigned)b) << 16);
}

using short8 = __attribute__((ext_vector_type(8))) short;
using f32x4 = __attribute__((ext_vector_type(4))) float;

// ---------------------------------------------------------------------------
// one-time: split comp_W into bf16 hi/lo, rearranged to [5120][512]
// ---------------------------------------------------------------------------
__global__ __launch_bounds__(256) void splitW_k(const float* __restrict__ comp_W,
                                                unsigned short* __restrict__ Wh,
                                                unsigned short* __restrict__ Wl) {
    int t = (blockIdx.x * 256 + threadIdx.x) * 4;   // 5120*512 elems, 4/thread
    int n = t >> 9;
    int k = t & 511;
    const float* src = (n < GG) ? (comp_W + (size_t)n * (2 * DD) + k)
                                : (comp_W + (size_t)(n - GG) * (2 * DD) + DD + k);
    float4 v = *(const float4*)src;
    ushort4 h, l;
    h.x = f2bf(v.x); l.x = f2bf(v.x - bf2f(h.x));
    h.y = f2bf(v.y); l.y = f2bf(v.y - bf2f(h.y));
    h.z = f2bf(v.z); l.z = f2bf(v.z - bf2f(h.z));
    h.w = f2bf(v.w); l.w = f2bf(v.w - bf2f(h.w));
    *(ushort4*)(Wh + t) = h;
    *(ushort4*)(Wl + t) = l;
}

// ---------------------------------------------------------------------------
// generic flat bf16 hi/lo split (layout-preserving; rows already K-contiguous)
// ---------------------------------------------------------------------------
__global__ __launch_bounds__(256) void splitF_k(const float* __restrict__ src,
                                                unsigned short* __restrict__ dh,
                                                unsigned short* __restrict__ dl) {
    int t = (blockIdx.x * 256 + threadIdx.x) * 4;
    float4 v = *(const float4*)(src + t);
    ushort4 h, l;
    h.x = f2bf(v.x); l.x = f2bf(v.x - bf2f(h.x));
    h.y = f2bf(v.y); l.y = f2bf(v.y - bf2f(h.y));
    h.z = f2bf(v.z); l.z = f2bf(v.z - bf2f(h.z));
    h.w = f2bf(v.w); l.w = f2bf(v.w - bf2f(h.w));
    *(ushort4*)(dh + t) = h;
    *(ushort4*)(dl + t) = l;
}

// ---------------------------------------------------------------------------
// gemm64w_mfma: word projection via bf16x3 MFMA. M=1536, N=1024, K=512.
// O[m][n] = sum_k inp[m][k]*word_W[n][k] + bias[n].
// 192 blocks (64m x 128n tile), 4 waves 2x2 (wave = 32m x 64n = 2x4 16-tiles),
// BK=64 LDS-staged, padded [.][72] rows (v3-verified layout).
// Epilogue: n<512 -> h as bf16 hi/lo (Ah/Al); n>=512 -> c as fp32 (O1).
// ---------------------------------------------------------------------------
__global__ __launch_bounds__(256) void gemm64w_mfma(
    const unsigned short* __restrict__ Ih, const unsigned short* __restrict__ Il,
    const unsigned short* __restrict__ Vh, const unsigned short* __restrict__ Vl,
    const float* __restrict__ bias,
    unsigned short* __restrict__ Ah, unsigned short* __restrict__ Al,
    float* __restrict__ O1) {
    __shared__ unsigned short AhS[64][72];
    __shared__ unsigned short AlS[64][72];
    __shared__ unsigned short BhS[128][72];
    __shared__ unsigned short BlS[128][72];

    const int tid = threadIdx.x;
    const int m0 = (blockIdx.x % 24) * 64;
    const int n0 = (blockIdx.x / 24) * 128;

    const int w = tid >> 6, lane = tid & 63;
    const int mq = w >> 1, nq = w & 1;
    const int lr = lane & 15, kg = lane >> 4;

    const int srow = tid >> 3;   // 0..31 (+it*32)
    const int sk8 = tid & 7;

    const unsigned short* agh = Ih + (size_t)(m0 + srow) * DD + sk8 * 8;
    const unsigned short* agl = Il + (size_t)(m0 + srow) * DD + sk8 * 8;
    const unsigned short* bgh = Vh + (size_t)(n0 + srow) * DD + sk8 * 8;
    const unsigned short* bgl = Vl + (size_t)(n0 + srow) * DD + sk8 * 8;

    f32x4 acc[2][4];
#pragma unroll
    for (int mt = 0; mt < 2; ++mt)
#pragma unroll
        for (int nt = 0; nt < 4; ++nt) acc[mt][nt] = (f32x4){0.f, 0.f, 0.f, 0.f};

    short8 rAh[2], rAl[2], rBh[4], rBl[4];

#define LOADT(kt)                                                            \
    {                                                                        \
        _Pragma("unroll")                                                    \
        for (int it = 0; it < 2; ++it) {                                     \
            const size_t ro = (size_t)it * 32 * DD + (kt);                   \
            rAh[it] = *(const short8*)(agh + ro);                            \
            rAl[it] = *(const short8*)(agl + ro);                            \
        }                                                                    \
        _Pragma("unroll")                                                    \
        for (int it = 0; it < 4; ++it) {                                     \
            const size_t ro = (size_t)it * 32 * DD + (kt);                   \
            rBh[it] = *(const short8*)(bgh + ro);                            \
            rBl[it] = *(const short8*)(bgl + ro);                            \
        }                                                                    \
    }
#define WRITET()                                                             \
    {                                                                        \
        _Pragma("unroll")                                                    \
        for (int it = 0; it < 2; ++it) {                                     \
            const int row = srow + it * 32;                                  \
            *(short8*)&AhS[row][sk8 * 8] = rAh[it];                          \
            *(short8*)&AlS[row][sk8 * 8] = rAl[it];                          \
        }                                                                    \
        _Pragma("unroll")                                                    \
        for (int it = 0; it < 4; ++it) {                                     \
            const int row = srow + it * 32;                                  \
            *(short8*)&BhS[row][sk8 * 8] = rBh[it];                          \
            *(short8*)&BlS[row][sk8 * 8] = rBl[it];                          \
        }                                                                    \
    }

    LOADT(0);
    WRITET();
    __syncthreads();

    for (int kti = 0; kti < 8; ++kti) {
        if (kti + 1 < 8) LOADT((kti + 1) * 64);
#pragma unroll
        for (int ks2 = 0; ks2 < 2; ++ks2) {
            const int kb = ks2 * 32 + kg * 8;
            short8 fah[2], fal[2], fbh[4], fbl[4];
#pragma unroll
            for (int t = 0; t < 2; ++t) {
                fah[t] = *(const short8*)&AhS[mq * 32 + t * 16 + lr][kb];
                fal[t] = *(const short8*)&AlS[mq * 32 + t * 16 + lr][kb];
            }
#pragma unroll
            for (int t = 0; t < 4; ++t) {
                fbh[t] = *(const short8*)&BhS[nq * 64 + t * 16 + lr][kb];
                fbl[t] = *(const short8*)&BlS[nq * 64 + t * 16 + lr][kb];
            }
#pragma unroll
            for (int mt = 0; mt < 2; ++mt)
#pragma unroll
                for (int nt = 0; nt < 4; ++nt) {
                    acc[mt][nt] = __builtin_amdgcn_mfma_f32_16x16x32_bf16(fal[mt], fbh[nt], acc[mt][nt], 0, 0, 0);
                    acc[mt][nt] = __builtin_amdgcn_mfma_f32_16x16x32_bf16(fah[mt], fbl[nt], acc[mt][nt], 0, 0, 0);
                    acc[mt][nt] = __builtin_amdgcn_mfma_f32_16x16x32_bf16(fah[mt], fbh[nt], acc[mt][nt], 0, 0, 0);
                }
        }
        __syncthreads();
        if (kti + 1 < 8) {
            WRITET();
            __syncthreads();
        }
    }
#undef LOADT
#undef WRITET

    // C/D layout: col = lane&15, row = (lane>>4)*4 + reg   [verified]
#pragma unroll
    for (int mt = 0; mt < 2; ++mt) {
        const int mbase = m0 + mq * 32 + mt * 16 + kg * 4;
#pragma unroll
        for (int nt = 0; nt < 4; ++nt) {
            const int n = n0 + nq * 64 + nt * 16 + lr;
            const float bv = bias[n];
#pragma unroll
            for (int r = 0; r < 4; ++r) {
                const int m = mbase + r;
                float v = acc[mt][nt][r] + bv;
                if (n < DD) {
                    unsigned short hv = f2bf(v);
                    Ah[(size_t)m * DD + n] = hv;
                    Al[(size_t)m * DD + n] = f2bf(v - bf2f(hv));
                } else {
                    O1[(size_t)m * DD + (n - DD)] = v;
                }
            }
        }
    }
}

// ---------------------------------------------------------------------------
// gemm_big_mfma v3: LDS-staged bf16x3 MFMA GEMM. M=1536, N=5120, K=512.
// (round-6 verified)
// ---------------------------------------------------------------------------
__global__ __launch_bounds__(256) void gemm_big_mfma(
    const unsigned short* __restrict__ Ah, const unsigned short* __restrict__ Al,
    const unsigned short* __restrict__ Wh, const unsigned short* __restrict__ Wl,
    float* __restrict__ O0, float* __restrict__ O1) {
    __shared__ unsigned short AhS[128][72];
    __shared__ unsigned short AlS[128][72];
    __shared__ unsigned short BhS[128][72];
    __shared__ unsigned short BlS[128][72];

    const int tid = threadIdx.x;
    const int xcd = blockIdx.x & 7, idx = blockIdx.x >> 3;
    const int n0 = (xcd * 5 + idx % 5) * 128;
    const int m0 = (idx / 5) * 128;

    const int w = tid >> 6, lane = tid & 63;
    const int mq = w >> 1, nq = w & 1;
    const int lr = lane & 15, kg = lane >> 4;

    const int srow = tid >> 3;
    const int sk8 = tid & 7;

    const unsigned short* agh = Ah + (size_t)(m0 + srow) * DD + sk8 * 8;
    const unsigned short* agl = Al + (size_t)(m0 + srow) * DD + sk8 * 8;
    const unsigned short* bgh = Wh + (size_t)(n0 + srow) * DD + sk8 * 8;
    const unsigned short* bgl = Wl + (size_t)(n0 + srow) * DD + sk8 * 8;

    f32x4 acc[4][4];
#pragma unroll
    for (int mt = 0; mt < 4; ++mt)
#pragma unroll
        for (int nt = 0; nt < 4; ++nt) acc[mt][nt] = (f32x4){0.f, 0.f, 0.f, 0.f};

    short8 rAh[4], rAl[4], rBh[4], rBl[4];

#define LOADT(kt)                                                            \
    {                                                                        \
        _Pragma("unroll")                                                    \
        for (int it = 0; it < 4; ++it) {                                     \
            const size_t ro = (size_t)it * 32 * DD + (kt);                   \
            rAh[it] = *(const short8*)(agh + ro);                            \
            rAl[it] = *(const short8*)(agl + ro);                            \
            rBh[it] = *(const short8*)(bgh + ro);                            \
            rBl[it] = *(const short8*)(bgl + ro);                            \
        }                                                                    \
    }
#define WRITET()                                                             \
    {                                                                        \
        _Pragma("unroll")                                                    \
        for (int it = 0; it < 4; ++it) {                                     \
            const int row = srow + it * 32;                                  \
            *(short8*)&AhS[row][sk8 * 8] = rAh[it];                          \
            *(short8*)&AlS[row][sk8 * 8] = rAl[it];                          \
            *(short8*)&BhS[row][sk8 * 8] = rBh[it];                          \
            *(short8*)&BlS[row][sk8 * 8] = rBl[it];                          \
        }                                                                    \
    }

    LOADT(0);
    WRITET();
    __syncthreads();

    for (int kti = 0; kti < 8; ++kti) {
        if (kti + 1 < 8) LOADT((kti + 1) * 64);
#pragma unroll
        for (int ks2 = 0; ks2 < 2; ++ks2) {
            const int kb = ks2 * 32 + kg * 8;
            short8 fah[4], fal[4], fbh[4], fbl[4];
#pragma unroll
            for (int t = 0; t < 4; ++t) {
                fah[t] = *(const short8*)&AhS[mq * 64 + t * 16 + lr][kb];
                fal[t] = *(const short8*)&AlS[mq * 64 + t * 16 + lr][kb];
                fbh[t] = *(const short8*)&BhS[nq * 64 + t * 16 + lr][kb];
                fbl[t] = *(const short8*)&BlS[nq * 64 + t * 16 + lr][kb];
            }
#pragma unroll
            for (int mt = 0; mt < 4; ++mt)
#pragma unroll
                for (int nt = 0; nt < 4; ++nt) {
                    acc[mt][nt] = __builtin_amdgcn_mfma_f32_16x16x32_bf16(fal[mt], fbh[nt], acc[mt][nt], 0, 0, 0);
                    acc[mt][nt] = __builtin_amdgcn_mfma_f32_16x16x32_bf16(fah[mt], fbl[nt], acc[mt][nt], 0, 0, 0);
                    acc[mt][nt] = __builtin_amdgcn_mfma_f32_16x16x32_bf16(fah[mt], fbh[nt], acc[mt][nt], 0, 0, 0);
                }
        }
        __syncthreads();
        if (kti + 1 < 8) {
            WRITET();
            __syncthreads();
        }
    }
#undef LOADT
#undef WRITET

#pragma unroll
    for (int mt = 0; mt < 4; ++mt) {
        const int mbase = m0 + mq * 64 + mt * 16 + kg * 4;
#pragma unroll
        for (int nt = 0; nt < 4; ++nt) {
            const int n = n0 + nq * 64 + nt * 16 + lr;
#pragma unroll
            for (int r = 0; r < 4; ++r) {
                const int m = mbase + r;
                float* dst = (n < GG) ? (O0 + (size_t)m * GG + n)
                                      : (O1 + (size_t)m * GG + (n - GG));
                *dst = acc[mt][nt][r];
            }
        }
    }
}

// ---------------------------------------------------------------------------
// half-block (128-lane) candidate scorer
// ---------------------------------------------------------------------------
__device__ __forceinline__ float half_dot(const float* __restrict__ ar,
                                          const float* __restrict__ br,
                                          const float* __restrict__ cb,
                                          const float* __restrict__ cl,
                                          const float* __restrict__ cr,
                                          const float* __restrict__ q, int lane) {
    float part = 0.f;
#pragma unroll
    for (int d = lane; d < DD; d += 128) {
        float gi = ar[d] + br[d] + cb[d];
        float gfl = ar[DD + d] + br[DD + d] + cb[DD + d];
        float gfr = ar[2 * DD + d] + br[2 * DD + d] + cb[2 * DD + d];
        float gu = ar[3 * DD + d] + br[3 * DD + d] + cb[3 * DD + d];
        float go = ar[4 * DD + d] + br[4 * DD + d] + cb[4 * DD + d];
        float nc = cl[d] * sigm(gfl + 1.f) + cr[d] * sigm(gfr + 1.f) + tanhf(gu) * sigm(gi);
        part += sigm(go) * tanhf(nc) * q[d];
    }
#pragma unroll
    for (int off = 32; off; off >>= 1) part += __shfl_down(part, off);
    return part;
}

// gate pair
__device__ __forceinline__ void gate2n(const float* __restrict__ ar,
                                       const float* __restrict__ br,
                                       const float* __restrict__ cb,
                                       const float* __restrict__ cl,
                                       const float* __restrict__ cr, int d,
                                       float nh[2], float nc[2]) {
    float2 A0 = *(const float2*)(ar + d),          B0 = *(const float2*)(br + d);
    float2 A1 = *(const float2*)(ar + DD + d),     B1 = *(const float2*)(br + DD + d);
    float2 A2 = *(const float2*)(ar + 2 * DD + d), B2 = *(const float2*)(br + 2 * DD + d);
    float2 A3 = *(const float2*)(ar + 3 * DD + d), B3 = *(const float2*)(br + 3 * DD + d);
    float2 A4 = *(const float2*)(ar + 4 * DD + d), B4 = *(const float2*)(br + 4 * DD + d);
    float2 C0 = *(const float2*)(cb + d);
    float2 C1 = *(const float2*)(cb + DD + d);
    float2 C2 = *(const float2*)(cb + 2 * DD + d);
    float2 C3 = *(const float2*)(cb + 3 * DD + d);
    float2 C4 = *(const float2*)(cb + 4 * DD + d);
    float2 CL = *(const float2*)(cl + d);
    float2 CR = *(const float2*)(cr + d);
    float gi0 = A0.x + B0.x + C0.x, gi1 = A0.y + B0.y + C0.y;
    float gfl0 = A1.x + B1.x + C1.x, gfl1 = A1.y + B1.y + C1.y;
    float gfr0 = A2.x + B2.x + C2.x, gfr1 = A2.y + B2.y + C2.y;
    float gu0 = A3.x + B3.x + C3.x, gu1 = A3.y + B3.y + C3.y;
    float go0 = A4.x + B4.x + C4.x, go1 = A4.y + B4.y + C4.y;
    nc[0] = CL.x * sigm(gfl0 + 1.f) + CR.x * sigm(gfr0 + 1.f) + tanhf(gu0) * sigm(gi0);
    nc[1] = CL.y * sigm(gfl1 + 1.f) + CR.y * sigm(gfr1 + 1.f) + tanhf(gu1) * sigm(gi1);
    nh[0] = sigm(go0) * tanhf(nc[0]);
    nh[1] = sigm(go1) * tanhf(nc[1]);
}

// ---------------------------------------------------------------------------
// initial scores: grid (12, 64)
// ---------------------------------------------------------------------------
__global__ __launch_bounds__(256) void scoreall_k(const float* __restrict__ acache,
                                                  const float* __restrict__ bcache,
                                                  const float* __restrict__ cbuf,
                                                  const float* __restrict__ compb,
                                                  const float* __restrict__ q,
                                                  float* __restrict__ scores_g) {
    __shared__ float red_s[4];
    const int tid = threadIdx.x;
    const int b = blockIdx.y;
    const int p = blockIdx.x * 2 + (tid >> 7);
    const bool valid = p < NSTEP;
    float w = 0.f;
    if (valid) {
        w = half_dot(acache + (size_t)(b * LL + p) * GG,
                     bcache + (size_t)(b * LL + p + 1) * GG, compb,
                     cbuf + (size_t)(b * LL + p) * DD,
                     cbuf + (size_t)(b * LL + p + 1) * DD, q, tid & 127);
    }
    if ((tid & 63) == 0) red_s[tid >> 6] = w;
    __syncthreads();
    if ((tid == 0 || tid == 128) && valid) {
        int base = tid >> 6;
        scores_g[b * NSTEP + p] = red_s[base] + red_s[base + 1];
    }
}

// ---------------------------------------------------------------------------
// stepA: 64 blocks (one per batch). rescore -> argmax -> merge -> hout (+bf16
// hi/lo split for the MFMA stepB) ; shift per-batch state (global).
// ---------------------------------------------------------------------------
__global__ __launch_bounds__(256) void stepA_k(
    int i, const int* __restrict__ length, float* __restrict__ cbuf,
    const float* __restrict__ acache, const float* __restrict__ bcache,
    float* __restrict__ hout, unsigned short* __restrict__ hh,
    unsigned short* __restrict__ hl, float* __restrict__ scores_g,
    int* __restrict__ seq_g, int* __restrict__ kp_g, int* __restrict__ msel,
    const float* __restrict__ compb, const float* __restrict__ q, float* __restrict__ out) {
    __shared__ float red_s[4];
    __shared__ float sc_l[32];
    __shared__ int seq_l[32];
    __shared__ int k_sh;
    const int tid = threadIdx.x;
    const int b = blockIdx.x;
    const int lane7 = tid & 127;
    const int lenb = length[b];
    const int ncand = NSTEP - i;

    if (i == 0) {
        if (tid < LL) seq_l[tid] = tid;
    } else {
        if (tid < LL - i) seq_l[tid] = seq_g[b * 32 + tid];
    }
    if (tid < ncand) sc_l[tid] = scores_g[b * NSTEP + tid];
    __syncthreads();
    const int kp = (i > 0) ? kp_g[b] : 0;

    if (i > 0 && i < lenb) {  // rescore candidates kp-1, kp (half-block each)
        int p = (tid < 128) ? (kp - 1) : kp;
        bool valid = (p >= 0) && (p < ncand);
        float w = 0.f;
        if (valid) {
            int sl = seq_l[p], sr = seq_l[p + 1];
            const float* ar = acache + (size_t)(b * LL + sl) * GG;
            const float* br = bcache + (size_t)(b * LL + sr) * GG;
            const float* cl = cbuf + (size_t)(b * LL + sl) * DD;
            const float* cr = cbuf + (size_t)(b * LL + sr) * DD;
#pragma unroll
            for (int pass = 0; pass < 2; ++pass) {
                int d = pass * 256 + lane7 * 2;
                float nh[2], nc[2];
                gate2n(ar, br, compb, cl, cr, d, nh, nc);
                float2 Q = *(const float2*)(q + d);
                w += nh[0] * Q.x + nh[1] * Q.y;
            }
#pragma unroll
            for (int off = 32; off; off >>= 1) w += __shfl_down(w, off);
        }
        if ((tid & 63) == 0) red_s[tid >> 6] = w;
        __syncthreads();
        if (tid == 0) {
            if (kp - 1 >= 0) sc_l[kp - 1] = red_s[0] + red_s[1];
            if (kp < ncand) sc_l[kp] = red_s[2] + red_s[3];
        }
        __syncthreads();
    }

    if (i + 1 < lenb) {
        if (tid == 0) {
            const int vmax = lenb - i - 2;
            int k = 0;
            float best = sc_l[0];
            for (int pp = 1; pp <= vmax; ++pp)
                if (sc_l[pp] > best) { best = sc_l[pp]; k = pp; }
            k_sh = k;
        }
        __syncthreads();
        const int k = k_sh;
        const int sl = seq_l[k], sr = seq_l[k + 1];
        const float* ar = acache + (size_t)(b * LL + sl) * GG;
        const float* br = bcache + (size_t)(b * LL + sr) * GG;
        const float* cl = cbuf + (size_t)(b * LL + sl) * DD;
        const float* cr = cbuf + (size_t)(b * LL + sr) * DD;
        {
            const int d = 2 * tid;
            float nh[2], nc[2];
            gate2n(ar, br, compb, cl, cr, d, nh, nc);
            *(float2*)(cbuf + (size_t)(b * LL + sl) * DD + d) = make_float2(nc[0], nc[1]);
            *(float2*)(hout + (size_t)b * DD + d) = make_float2(nh[0], nh[1]);
            // bf16 hi/lo split for stepB's MFMA A-operand
            ushort2 hv, lv;
            hv.x = f2bf(nh[0]); lv.x = f2bf(nh[0] - bf2f(hv.x));
            hv.y = f2bf(nh[1]); lv.y = f2bf(nh[1] - bf2f(hv.y));
            *(ushort2*)(hh + (size_t)b * DD + d) = hv;
            *(ushort2*)(hl + (size_t)b * DD + d) = lv;
            if (i == NSTEP - 1)
                *(float2*)(out + (size_t)b * DD + d) = make_float2(nh[0], nh[1]);
        }
        float sv = (tid + 1 < ncand) ? sc_l[tid + 1] : 0.f;
        int qv = (tid + 1 < LL - i) ? seq_l[tid + 1] : 0;
        __syncthreads();
        if (tid >= k + 1 && tid <= ncand - 2) sc_l[tid] = sv;
        if (tid >= k + 1 && tid <= LL - i - 2) seq_l[tid] = qv;
        if (tid < ncand - 1) scores_g[b * NSTEP + tid] = sc_l[tid];
        if (tid < LL - i - 1) seq_g[b * 32 + tid] = seq_l[tid];
        if (tid == 0) { kp_g[b] = k; msel[b] = sl; }
    } else if (i == NSTEP - 1) {
        const int d = 2 * tid;
        *(float2*)(out + (size_t)b * DD + d) = *(const float2*)(hout + (size_t)b * DD + d);
    }
}

// ---------------------------------------------------------------------------
// stepB via bf16x3 MFMA: O[m][n] = sum_k hout[m][k]*W[n][k], M=64, N=32/block,
// K=512. 4 waves: wave w owns m-tiles {2*(w>>1), 2*(w>>1)+1} x n-tile (w&1).
// ---------------------------------------------------------------------------
__global__ __launch_bounds__(256) void stepB_mfma(
    const unsigned short* __restrict__ hh, const unsigned short* __restrict__ hl,
    const int* __restrict__ msel,
    const unsigned short* __restrict__ Wh, const unsigned short* __restrict__ Wl,
    float* __restrict__ acache, float* __restrict__ bcache) {
    __shared__ int msel_s[BB];
    const int tid = threadIdx.x;
    const int bid = blockIdx.x;
    if (tid < BB) msel_s[tid] = msel[tid];
    __syncthreads();

    const int w = tid >> 6, lane = tid & 63;
    const int mt0 = (w >> 1) * 2;           // this wave's first m-tile
    const int nt = w & 1;                   // this wave's n-tile
    const int lr = lane & 15;
    const int kg = lane >> 4;               // k-group (8 contiguous k)
    const int n = bid * 32 + nt * 16 + lr;  // global output column

    const unsigned short* wh_row = Wh + (size_t)n * DD;
    const unsigned short* wl_row = Wl + (size_t)n * DD;
    const unsigned short* a0h_row = hh + (size_t)(mt0 * 16 + lr) * DD;
    const unsigned short* a0l_row = hl + (size_t)(mt0 * 16 + lr) * DD;
    const unsigned short* a1h_row = a0h_row + 16 * DD;
    const unsigned short* a1l_row = a0l_row + 16 * DD;

    f32x4 acc0 = {0.f, 0.f, 0.f, 0.f};
    f32x4 acc1 = {0.f, 0.f, 0.f, 0.f};

#pragma unroll 4
    for (int ks = 0; ks < 16; ++ks) {
        const int kb = ks * 32 + kg * 8;
        short8 bh = *(const short8*)(wh_row + kb);
        short8 bl = *(const short8*)(wl_row + kb);
        short8 a0h = *(const short8*)(a0h_row + kb);
        short8 a0l = *(const short8*)(a0l_row + kb);
        short8 a1h = *(const short8*)(a1h_row + kb);
        short8 a1l = *(const short8*)(a1l_row + kb);
        acc0 = __builtin_amdgcn_mfma_f32_16x16x32_bf16(a0h, bh, acc0, 0, 0, 0);
        acc1 = __builtin_amdgcn_mfma_f32_16x16x32_bf16(a1h, bh, acc1, 0, 0, 0);
        acc0 = __builtin_amdgcn_mfma_f32_16x16x32_bf16(a0l, bh, acc0, 0, 0, 0);
        acc1 = __builtin_amdgcn_mfma_f32_16x16x32_bf16(a1l, bh, acc1, 0, 0, 0);
        acc0 = __builtin_amdgcn_mfma_f32_16x16x32_bf16(a0h, bl, acc0, 0, 0, 0);
        acc1 = __builtin_amdgcn_mfma_f32_16x16x32_bf16(a1h, bl, acc1, 0, 0, 0);
    }

    // write: n fixed per lane; rows m = mt*16 + kg*4 + r, scattered by msel
#pragma unroll
    for (int t = 0; t < 2; ++t) {
        f32x4 acc = t ? acc1 : acc0;
        const int mbase = (mt0 + t) * 16 + kg * 4;
#pragma unroll
        for (int r = 0; r < 4; ++r) {
            int m = mbase + r;
            size_t row = (size_t)(m * LL + msel_s[m]);
            float* dst = (n < GG) ? (acache + row * GG + n)
                                  : (bcache + row * GG + (n - GG));
            *dst = acc[r];
        }
    }
}

// ---------------------------------------------------------------------------
extern "C" void kernel_launch(void* const* d_in, const int* in_sizes, int n_in, void* d_out,
                              int out_size, void* d_ws, size_t ws_size, hipStream_t stream) {
    const float* inp = (const float*)d_in[0];
    const int* length = (const int*)d_in[1];
    const float* word_W = (const float*)d_in[2];
    const float* word_b = (const float*)d_in[3];
    const float* comp_W = (const float*)d_in[4];
    const float* comp_b = (const float*)d_in[5];
    const float* comp_q = (const float*)d_in[6];
    float* out = (float*)d_out;

    float* ws = (float*)d_ws;
    size_t off = 0;
    float* cbuf = ws + off;   off += (size_t)BB * LL * DD;
    float* acache = ws + off; off += (size_t)BB * LL * GG;
    float* bcache = ws + off; off += (size_t)BB * LL * GG;
    float* hout = ws + off;   off += (size_t)BB * DD;
    float* scores = ws + off; off += 2048;
    int* seq_g = (int*)(ws + off); off += BB * 32;
    int* kp_g = (int*)(ws + off);  off += 64;
    int* msel = (int*)(ws + off);  off += 64;
    unsigned short* Wh = (unsigned short*)(ws + off); off += (size_t)5120 * DD / 2;
    unsigned short* Wl = (unsigned short*)(ws + off); off += (size_t)5120 * DD / 2;
    unsigned short* hh = (unsigned short*)(ws + off); off += (size_t)BB * DD / 2;
    unsigned short* hl = (unsigned short*)(ws + off); off += (size_t)BB * DD / 2;
    unsigned short* Ah = (unsigned short*)(ws + off); off += (size_t)BB * LL * DD / 2;
    unsigned short* Al = (unsigned short*)(ws + off); off += (size_t)BB * LL * DD / 2;
    unsigned short* Ih = (unsigned short*)(ws + off); off += (size_t)BB * LL * DD / 2;
    unsigned short* Il = (unsigned short*)(ws + off); off += (size_t)BB * LL * DD / 2;
    unsigned short* Vh = (unsigned short*)(ws + off); off += (size_t)1024 * DD / 2;
    unsigned short* Vl = (unsigned short*)(ws + off); off += (size_t)1024 * DD / 2;
    (void)ws_size; (void)in_sizes; (void)n_in; (void)out_size;

    // one-time bf16 hi/lo splits
    splitW_k<<<2560, 256, 0, stream>>>(comp_W, Wh, Wl);                 // comp_W (rearranged)
    splitF_k<<<768, 256, 0, stream>>>(inp, Ih, Il);                     // inp [1536][512]
    splitF_k<<<512, 256, 0, stream>>>(word_W, Vh, Vl);                  // word_W [1024][512]

    // word projection via bf16x3 MFMA: h (bf16 hi/lo) + c (fp32)
    gemm64w_mfma<<<192, 256, 0, stream>>>(Ih, Il, Vh, Vl, word_b, Ah, Al, cbuf);

    // a/b caches for all 1536 items via LDS-staged bf16x3 MFMA (v3)
    gemm_big_mfma<<<480, 256, 0, stream>>>(Ah, Al, Wh, Wl, acache, bcache);

    // initial candidate scores
    scoreall_k<<<dim3(12, 64), 256, 0, stream>>>(acache, bcache, cbuf, comp_b, comp_q, scores);

    // 23 merge steps: A (select+merge) then B (bf16x3 MFMA GEMM for merged rows)
    for (int i = 0; i < NSTEP; ++i) {
        stepA_k<<<BB, 256, 0, stream>>>(i, length, cbuf, acache, bcache, hout, hh, hl,
                                        scores, seq_g, kp_g, msel, comp_b, comp_q, out);
        if (i < NSTEP - 1) {
            stepB_mfma<<<NTILES, 256, 0, stream>>>(hh, hl, msel, Wh, Wl, acache, bcache);
        }
    }
}